// Round 7
// baseline (258.685 us; speedup 1.0000x reference)
//
#include <hip/hip_runtime.h>
#include <hip/hip_bf16.h>

// GCNConv: out = relu( D^{-1/2} (A + I) D^{-1/2} (x @ W) + b )
// CSR build via atomic-free two-phase bucket sort (bucket = dst>>7):
//   1. k_hist   : per-block LDS histograms -> hist[bucket][block] (+ Wt convert)
//   2. k_scanrow: per-bucket exclusive scan of the 512 block columns (+ btotal)
//   3. k_scanb  : single block scans 782 bucket totals -> bbase
//   4. k_scatter: edges -> bucket-grouped packed array (src | dlow<<17)
//   5. k_csr    : per-bucket LDS hist+scan+rank -> csr_src, rowptr[N+1], dinv
//   6. k_gemm   : xs = bf16( dinv[n] * (x[n] @ W) ) via MFMA 16x16x32 bf16
//                 (split into 2 row-halves THIS ROUND for profile visibility)
//   7. k_aggregate: 4 nodes/wave, 8 gathers in flight, csr prefetch, NT stores
//                 (split into 4 node-quarters THIS ROUND for profile visibility;
//                  the ~62us aggregate monopolized the top-5 dispatch table —
//                  quarters at ~16us let every >16us kernel surface)
// Harness rule (rounds 1&5 failures): NO cooperative launch, NO inter-block
// spin — graph capture kills both. Plain launches only.

#define NP1 512          // blocks in phase-1 (hist/scatter): 2 per CU
#define MAXB 1024        // static LDS cap on bucket count (N <= 131072)

typedef short  short8 __attribute__((ext_vector_type(8)));
typedef float  f32x4  __attribute__((ext_vector_type(4)));

__device__ inline unsigned short f2b(float f) {   // fp32 -> bf16 RNE
    unsigned u = __float_as_uint(f);
    return (unsigned short)((u + 0x7fffu + ((u >> 16) & 1u)) >> 16);
}

__device__ inline void acc4(float4& a, unsigned lo, unsigned hi) {
    a.x += __uint_as_float(lo << 16);
    a.y += __uint_as_float(lo & 0xffff0000u);
    a.z += __uint_as_float(hi << 16);
    a.w += __uint_as_float(hi & 0xffff0000u);
}

// ---- phase 1: bucket histogram (+ fused Wt = bf16(W^T)) -----------------
__global__ __launch_bounds__(256) void k_hist(const int* __restrict__ dst,
                                              int* __restrict__ hist,
                                              const float* __restrict__ W,
                                              unsigned short* __restrict__ Wt,
                                              int E, int B, int chunk) {
    __shared__ int h[MAXB];
    for (int i = threadIdx.x; i < B; i += 256) h[i] = 0;
    __syncthreads();
    int e0 = blockIdx.x * chunk;
    int e1 = min(E, e0 + chunk);
    for (int e = e0 + threadIdx.x; e < e1; e += 256)
        atomicAdd(&h[dst[e] >> 7], 1);
    __syncthreads();
    for (int i = threadIdx.x; i < B; i += 256)
        hist[i * NP1 + blockIdx.x] = h[i];
    if (blockIdx.x < 64) {                      // fused weight transpose
        int i = blockIdx.x * 256 + threadIdx.x; // 0..16383
        int k = i >> 7, n = i & 127;
        Wt[n * 128 + k] = f2b(W[k * 128 + n]);
    }
}

// ---- phase 2a: per-bucket exclusive scan over the NP1 block columns -----
__global__ __launch_bounds__(256) void k_scanrow(int* __restrict__ hist,
                                                 int* __restrict__ btotal, int B) {
    __shared__ int s[256];
    const int b = blockIdx.x;
    const int t = threadIdx.x;
    int v0 = hist[b * NP1 + 2 * t];
    int v1 = hist[b * NP1 + 2 * t + 1];
    int pair = v0 + v1;
    s[t] = pair;
    __syncthreads();
    for (int off = 1; off < 256; off <<= 1) {
        int add = (t >= off) ? s[t - off] : 0;
        __syncthreads();
        s[t] += add;
        __syncthreads();
    }
    int exc = s[t] - pair;                      // exclusive prefix of this pair
    hist[b * NP1 + 2 * t]     = exc;
    hist[b * NP1 + 2 * t + 1] = exc + v0;
    if (t == 255) btotal[b] = s[255];
}

// ---- phase 2b: single block scans bucket totals -> bbase (exclusive) ----
__global__ __launch_bounds__(256) void k_scanb(const int* __restrict__ btotal,
                                               int* __restrict__ bbase, int B) {
    __shared__ int s[256];
    const int t = threadIdx.x;
    int v[4];
    int loc = 0;
#pragma unroll
    for (int k = 0; k < 4; ++k) {
        int idx = t * 4 + k;
        v[k] = (idx < B) ? btotal[idx] : 0;
        loc += v[k];
    }
    s[t] = loc;
    __syncthreads();
    for (int off = 1; off < 256; off <<= 1) {
        int add = (t >= off) ? s[t - off] : 0;
        __syncthreads();
        s[t] += add;
        __syncthreads();
    }
    int run = s[t] - loc;
#pragma unroll
    for (int k = 0; k < 4; ++k) {
        int idx = t * 4 + k;
        if (idx < B) bbase[idx] = run;
        run += v[k];
    }
}

// ---- phase 3: bucket-grouped scatter (LDS cursors) ---------------------
__global__ __launch_bounds__(256) void k_scatter(const int* __restrict__ src,
                                                 const int* __restrict__ dst,
                                                 const int* __restrict__ hist,
                                                 const int* __restrict__ bbase,
                                                 unsigned* __restrict__ bucketed,
                                                 int E, int B, int chunk) {
    __shared__ int cur[MAXB];
    for (int i = threadIdx.x; i < B; i += 256)
        cur[i] = bbase[i] + hist[i * NP1 + blockIdx.x];
    __syncthreads();
    int e0 = blockIdx.x * chunk;
    int e1 = min(E, e0 + chunk);
    for (int e = e0 + threadIdx.x; e < e1; e += 256) {
        int d = dst[e];
        int p = atomicAdd(&cur[d >> 7], 1);   // LDS atomic
        bucketed[p] = (unsigned)src[e] | ((unsigned)(d & 127) << 17);
    }
}

// ---- phase 4: per-bucket CSR finalize -----------------------------------
__global__ __launch_bounds__(256) void k_csr(const unsigned* __restrict__ bucketed,
                                             const int* __restrict__ bbase,
                                             const int* __restrict__ btotal,
                                             int* __restrict__ csr_src,
                                             int* __restrict__ rowptr,   // N+1
                                             float* __restrict__ dinv_g,
                                             int E, int B, int N) {
    const int b = blockIdx.x;
    const int t = threadIdx.x;
    const int base = bbase[b];
    const int cnt = btotal[b];
    const int node0 = b << 7;

    __shared__ int sdeg[128], sscan[128], cur[128];
    if (t < 128) sdeg[t] = 0;
    __syncthreads();
    for (int i = t; i < cnt; i += 256)
        atomicAdd(&sdeg[bucketed[base + i] >> 17], 1);
    __syncthreads();
    if (t < 128) sscan[t] = sdeg[t];
    __syncthreads();
    for (int off = 1; off < 128; off <<= 1) {
        int add = 0;
        if (t < 128 && t >= off) add = sscan[t - off];
        __syncthreads();
        if (t < 128) sscan[t] += add;
        __syncthreads();
    }
    if (t < 128) {
        int rs = sscan[t] - sdeg[t];   // exclusive
        cur[t] = rs;
        int node = node0 + t;
        if (node < N) {
            rowptr[node] = base + rs;
            dinv_g[node] = rsqrtf((float)(sdeg[t] + 1));   // +1 self-loop
        }
    }
    if (b == B - 1 && t == 0) rowptr[N] = E;
    __syncthreads();
    for (int i = t; i < cnt; i += 256) {
        unsigned w = bucketed[base + i];
        int p = atomicAdd(&cur[w >> 17], 1);   // LDS atomic
        csr_src[base + p] = (int)(w & 0x1FFFFu);
    }
}

// ---- MFMA gemm: xs = bf16(dinv * (x @ W)), packed bf16x2 ----------------
// row_base: starting row of this dispatch (profile-visibility split).
// Also writes a zeroed dummy row at index N (aggregate tail-gather target).
__global__ __launch_bounds__(256) void k_gemm(const float* __restrict__ x,
                                              const unsigned short* __restrict__ Wt,
                                              const float* __restrict__ dinv,
                                              unsigned* __restrict__ xs_out,
                                              int N, int row_base) {
    __shared__ short out_lds[4][16][136];
    const int t = threadIdx.x;
    const int wv = t >> 6;
    const int lane = t & 63;
    const int quad = lane >> 4;
    const int lid = lane & 15;
    const int row0 = row_base + blockIdx.x * 64;

    int grow = row0 + wv * 16 + lid;
    int growc = grow < N ? grow : N - 1;
    short8 af[4];
#pragma unroll
    for (int q = 0; q < 4; ++q) {
        const float4* xr = (const float4*)(x + (size_t)growc * 128 + q * 32 + quad * 8);
        float4 f0 = xr[0], f1 = xr[1];
        af[q][0] = (short)f2b(f0.x); af[q][1] = (short)f2b(f0.y);
        af[q][2] = (short)f2b(f0.z); af[q][3] = (short)f2b(f0.w);
        af[q][4] = (short)f2b(f1.x); af[q][5] = (short)f2b(f1.y);
        af[q][6] = (short)f2b(f1.z); af[q][7] = (short)f2b(f1.w);
    }

    int drow = row0 + wv * 16 + quad * 4;
    float4 dv4;
    if (drow + 3 < N)      dv4 = *(const float4*)(dinv + drow);
    else {
        dv4.x = dinv[min(drow + 0, N - 1)];
        dv4.y = dinv[min(drow + 1, N - 1)];
        dv4.z = dinv[min(drow + 2, N - 1)];
        dv4.w = dinv[min(drow + 3, N - 1)];
    }

#pragma unroll
    for (int c = 0; c < 8; ++c) {
        f32x4 acc = {0.f, 0.f, 0.f, 0.f};
#pragma unroll
        for (int q = 0; q < 4; ++q) {
            const short8* bp = (const short8*)(Wt + (size_t)(c * 16 + lid) * 128 +
                                               q * 32 + quad * 8);
            acc = __builtin_amdgcn_mfma_f32_16x16x32_bf16(af[q], *bp, acc, 0, 0, 0);
        }
        out_lds[wv][quad * 4 + 0][c * 16 + lid] = (short)f2b(acc[0] * dv4.x);
        out_lds[wv][quad * 4 + 1][c * 16 + lid] = (short)f2b(acc[1] * dv4.y);
        out_lds[wv][quad * 4 + 2][c * 16 + lid] = (short)f2b(acc[2] * dv4.z);
        out_lds[wv][quad * 4 + 3][c * 16 + lid] = (short)f2b(acc[3] * dv4.w);
    }
    __syncthreads();

    int rl = lane >> 2;
    int cseg = lane & 3;
    int grow2 = row0 + wv * 16 + rl;
    if (grow2 <= N) {
        uint4* dstp = (uint4*)(xs_out + (size_t)grow2 * 64);
        if (grow2 < N) {
            const uint4* srcp = (const uint4*)((const char*)&out_lds[wv][rl][0] + cseg * 64);
#pragma unroll
            for (int tt = 0; tt < 4; ++tt) dstp[cseg * 4 + tt] = srcp[tt];
        } else {                                  // dummy zero row at index N
            uint4 z = make_uint4(0u, 0u, 0u, 0u);
#pragma unroll
            for (int tt = 0; tt < 4; ++tt) dstp[cseg * 4 + tt] = z;
        }
    }
}

// ---- aggregate: 4 nodes/wave, 16 lanes/node, 8 feats/lane ----------------
// [n_begin, n_end) node range per dispatch (profile-visibility split).
__global__ __launch_bounds__(256) void k_aggregate(const uint4* __restrict__ xs4,
                                                   const int* __restrict__ csr_src,
                                                   const int* __restrict__ rowptr,
                                                   const float* __restrict__ dinv,
                                                   const float* __restrict__ bias,
                                                   float* __restrict__ out,
                                                   int N, int n_begin, int n_end) {
    const int t = threadIdx.x;
    const int lane = t & 63;
    const int sub = lane & 15;           // feature quarter: 8 floats (one uint4)
    const int gbase = lane & 48;         // 16-lane group base within wave
    const int n = n_begin + blockIdx.x * 16 + (t >> 4);
    if (n >= n_end) return;

    const int rs = rowptr[n];
    const int re = rowptr[n + 1];
    const float dv = dinv[n];
    const char* xb = (const char*)xs4;
    const unsigned subo = (unsigned)sub << 4;

    float4 a0 = make_float4(0.f, 0.f, 0.f, 0.f);
    float4 a1 = make_float4(0.f, 0.f, 0.f, 0.f);

    int idx = N;                                  // dummy zero row for tail slots
    if (rs + sub < re) idx = csr_src[rs + sub];

    for (int i0 = rs; i0 < re; i0 += 16) {
        const int idx_cur = idx;
        const int i1 = i0 + 16;
        idx = N;                                  // prefetch next round's index
        if (i1 + sub < re) idx = csr_src[i1 + sub];
        int m = re - i0; if (m > 16) m = 16;

        {   // slots 0..7: 8 gathers in flight
            int r0 = __shfl(idx_cur, gbase + 0);
            int r1 = __shfl(idx_cur, gbase + 1);
            int r2 = __shfl(idx_cur, gbase + 2);
            int r3 = __shfl(idx_cur, gbase + 3);
            int r4 = __shfl(idx_cur, gbase + 4);
            int r5 = __shfl(idx_cur, gbase + 5);
            int r6 = __shfl(idx_cur, gbase + 6);
            int r7 = __shfl(idx_cur, gbase + 7);
            uint4 u0 = *(const uint4*)(xb + ((((unsigned)r0) << 8) | subo));
            uint4 u1 = *(const uint4*)(xb + ((((unsigned)r1) << 8) | subo));
            uint4 u2 = *(const uint4*)(xb + ((((unsigned)r2) << 8) | subo));
            uint4 u3 = *(const uint4*)(xb + ((((unsigned)r3) << 8) | subo));
            uint4 u4 = *(const uint4*)(xb + ((((unsigned)r4) << 8) | subo));
            uint4 u5 = *(const uint4*)(xb + ((((unsigned)r5) << 8) | subo));
            uint4 u6 = *(const uint4*)(xb + ((((unsigned)r6) << 8) | subo));
            uint4 u7 = *(const uint4*)(xb + ((((unsigned)r7) << 8) | subo));
            acc4(a0, u0.x, u0.y); acc4(a1, u0.z, u0.w);
            acc4(a0, u1.x, u1.y); acc4(a1, u1.z, u1.w);
            acc4(a0, u2.x, u2.y); acc4(a1, u2.z, u2.w);
            acc4(a0, u3.x, u3.y); acc4(a1, u3.z, u3.w);
            acc4(a0, u4.x, u4.y); acc4(a1, u4.z, u4.w);
            acc4(a0, u5.x, u5.y); acc4(a1, u5.z, u5.w);
            acc4(a0, u6.x, u6.y); acc4(a1, u6.z, u6.w);
            acc4(a0, u7.x, u7.y); acc4(a1, u7.z, u7.w);
        }
        if (m > 8) {   // slots 8..15
            int r0 = __shfl(idx_cur, gbase + 8);
            int r1 = __shfl(idx_cur, gbase + 9);
            int r2 = __shfl(idx_cur, gbase + 10);
            int r3 = __shfl(idx_cur, gbase + 11);
            int r4 = __shfl(idx_cur, gbase + 12);
            int r5 = __shfl(idx_cur, gbase + 13);
            int r6 = __shfl(idx_cur, gbase + 14);
            int r7 = __shfl(idx_cur, gbase + 15);
            uint4 u0 = *(const uint4*)(xb + ((((unsigned)r0) << 8) | subo));
            uint4 u1 = *(const uint4*)(xb + ((((unsigned)r1) << 8) | subo));
            uint4 u2 = *(const uint4*)(xb + ((((unsigned)r2) << 8) | subo));
            uint4 u3 = *(const uint4*)(xb + ((((unsigned)r3) << 8) | subo));
            uint4 u4 = *(const uint4*)(xb + ((((unsigned)r4) << 8) | subo));
            uint4 u5 = *(const uint4*)(xb + ((((unsigned)r5) << 8) | subo));
            uint4 u6 = *(const uint4*)(xb + ((((unsigned)r6) << 8) | subo));
            uint4 u7 = *(const uint4*)(xb + ((((unsigned)r7) << 8) | subo));
            acc4(a0, u0.x, u0.y); acc4(a1, u0.z, u0.w);
            acc4(a0, u1.x, u1.y); acc4(a1, u1.z, u1.w);
            acc4(a0, u2.x, u2.y); acc4(a1, u2.z, u2.w);
            acc4(a0, u3.x, u3.y); acc4(a1, u3.z, u3.w);
            acc4(a0, u4.x, u4.y); acc4(a1, u4.z, u4.w);
            acc4(a0, u5.x, u5.y); acc4(a1, u5.z, u5.w);
            acc4(a0, u6.x, u6.y); acc4(a1, u6.z, u6.w);
            acc4(a0, u7.x, u7.y); acc4(a1, u7.z, u7.w);
        }
    }

    // self-loop (xs row n already dinv[n]-scaled)
    uint4 su = *(const uint4*)(xb + ((((unsigned)n) << 8) | subo));
    acc4(a0, su.x, su.y);
    acc4(a1, su.z, su.w);

    const float4* bp = (const float4*)bias;
    float4 b0 = bp[sub * 2];
    float4 b1 = bp[sub * 2 + 1];
    f32x4 o0, o1;
    o0[0] = fmaxf(dv * a0.x + b0.x, 0.f);
    o0[1] = fmaxf(dv * a0.y + b0.y, 0.f);
    o0[2] = fmaxf(dv * a0.z + b0.z, 0.f);
    o0[3] = fmaxf(dv * a0.w + b0.w, 0.f);
    o1[0] = fmaxf(dv * a1.x + b1.x, 0.f);
    o1[1] = fmaxf(dv * a1.y + b1.y, 0.f);
    o1[2] = fmaxf(dv * a1.z + b1.z, 0.f);
    o1[3] = fmaxf(dv * a1.w + b1.w, 0.f);

    f32x4* op = (f32x4*)(out + (size_t)n * 128 + sub * 8);
    __builtin_nontemporal_store(o0, op);          // out is write-once: don't
    __builtin_nontemporal_store(o1, op + 1);      // evict xs gather lines
}

extern "C" void kernel_launch(void* const* d_in, const int* in_sizes, int n_in,
                              void* d_out, int out_size, void* d_ws, size_t ws_size,
                              hipStream_t stream) {
    const float* x   = (const float*)d_in[0];
    const int*   ei  = (const int*)d_in[1];     // [2, E] flat: src then dst
    const float* W   = (const float*)d_in[2];
    const float* b   = (const float*)d_in[3];
    float*       out = (float*)d_out;

    const int N = in_sizes[0] / 128;
    const int E = in_sizes[1] / 2;
    const int* src = ei;
    const int* dst = ei + E;

    const int B = (N + 127) >> 7;            // 782 buckets (<= MAXB)
    const int M = B * NP1;                   // hist entries
    const int chunk = (E + NP1 - 1) / NP1;   // edges per phase-1 block

    // workspace carve (256B aligned)
    auto align = [](size_t v) { return (v + 255) & ~(size_t)255; };
    char* p = (char*)d_ws;
    int*            hist     = (int*)p;            p += align((size_t)M * 4);
    int*            btotal   = (int*)p;            p += align((size_t)B * 4);
    int*            bbase    = (int*)p;            p += align((size_t)B * 4);
    int*            rowptr   = (int*)p;            p += align(((size_t)N + 1) * 4);
    float*          dinv     = (float*)p;          p += align((size_t)N * 4);
    unsigned*       bucketed = (unsigned*)p;       p += align((size_t)E * 4);
    int*            csr_src  = (int*)p;            p += align((size_t)E * 4);
    unsigned*       xs       = (unsigned*)p;       p += align(((size_t)N + 1) * 64 * 4);
    unsigned short* Wt       = (unsigned short*)p; p += align(128 * 128 * 2);
    (void)ws_size;

    k_hist    <<<NP1, 256, 0, stream>>>(dst, hist, W, Wt, E, B, chunk);
    k_scanrow <<<B, 256, 0, stream>>>(hist, btotal, B);
    k_scanb   <<<1, 256, 0, stream>>>(btotal, bbase, B);
    k_scatter <<<NP1, 256, 0, stream>>>(src, dst, hist, bbase, bucketed, E, B, chunk);
    k_csr     <<<B, 256, 0, stream>>>(bucketed, bbase, btotal, csr_src, rowptr,
                                      dinv, E, B, N);

    // gemm split into 2 row-halves (profile visibility)
    const int half = ((N / 2) + 63) / 64 * 64;            // 50048
    const int g1 = half / 64;                             // blocks, first half
    const int g2 = (N + 1 - half + 63) / 64;              // covers dummy row N
    k_gemm <<<g1, 256, 0, stream>>>(x, Wt, dinv, xs, N, 0);
    k_gemm <<<g2, 256, 0, stream>>>(x, Wt, dinv, xs, N, half);

    // aggregate split into 4 node-quarters (profile visibility)
    const int q = (N + 3) / 4;
    for (int i = 0; i < 4; ++i) {
        int n0 = i * q;
        int n1 = min(N, n0 + q);
        if (n0 >= n1) break;
        int blocks = (n1 - n0 + 15) / 16;
        k_aggregate<<<blocks, 256, 0, stream>>>((const uint4*)xs, csr_src, rowptr,
                                                dinv, b, out, N, n0, n1);
    }
}

// Round 8
// 246.520 us; speedup vs baseline: 1.0493x; 1.0493x over previous
//
#include <hip/hip_runtime.h>
#include <hip/hip_bf16.h>

// GCNConv: out = relu( D^{-1/2} (A + I) D^{-1/2} (x @ W) + b )
// CSR build via atomic-free two-phase bucket sort (bucket = dst>>8, 256 nodes):
//   1. k_hist   : per-block LDS histograms -> hist[bucket][block] (+ Wt convert)
//   2. k_scanrow: per-bucket exclusive scan of the 512 block columns (+ btotal)
//   3. k_scatter: edges -> bucket-grouped packed array (src | dlow<<17);
//                 bucket bases computed by an in-block scan of btotal (no scanb)
//   4. k_csr    : per-bucket LDS hist+scan+rank -> csr_src, rowptr[N+1], dinv;
//                 bucket base via in-block scan of btotal
//   5. k_gemm   : xs = bf16( dinv[n] * (x[n] @ W) ) via MFMA 16x16x32 bf16
//                 (grid N/64+1: last block writes the zeroed dummy row N —
//                  rounds 3-6 never wrote it; tail gathers read raw workspace!)
//   6. k_aggregate: 4 nodes/wave, 8 gathers in flight, csr prefetch, NT stores
//                 (2 halves: keeps the 41us harness fills visible in top-5 so
//                  any kernel > 41us surfaces)
// Harness rules: NO cooperative launch, NO inter-block spin (graph capture).
// Harness poisons the 256MiB workspace every iteration (41us fill) — floor.

#define NP1 512          // blocks in phase-1 (hist/scatter): 2 per CU
#define BSH 8            // bucket shift: 256 nodes per bucket
#define MAXB 512         // bucket count cap (N <= 131072)

typedef short  short8 __attribute__((ext_vector_type(8)));
typedef float  f32x4  __attribute__((ext_vector_type(4)));

__device__ inline unsigned short f2b(float f) {   // fp32 -> bf16 RNE
    unsigned u = __float_as_uint(f);
    return (unsigned short)((u + 0x7fffu + ((u >> 16) & 1u)) >> 16);
}

__device__ inline void acc4(float4& a, unsigned lo, unsigned hi) {
    a.x += __uint_as_float(lo << 16);
    a.y += __uint_as_float(lo & 0xffff0000u);
    a.z += __uint_as_float(hi << 16);
    a.w += __uint_as_float(hi & 0xffff0000u);
}

// ---- phase 1: bucket histogram (+ fused Wt = bf16(W^T)) -----------------
__global__ __launch_bounds__(256) void k_hist(const int* __restrict__ dst,
                                              int* __restrict__ hist,
                                              const float* __restrict__ W,
                                              unsigned short* __restrict__ Wt,
                                              int E, int B, int chunk) {
    __shared__ int h[MAXB];
    for (int i = threadIdx.x; i < B; i += 256) h[i] = 0;
    __syncthreads();
    int e0 = blockIdx.x * chunk;
    int e1 = min(E, e0 + chunk);
    for (int e = e0 + threadIdx.x; e < e1; e += 256)
        atomicAdd(&h[dst[e] >> BSH], 1);
    __syncthreads();
    for (int i = threadIdx.x; i < B; i += 256)
        hist[i * NP1 + blockIdx.x] = h[i];
    if (blockIdx.x < 64) {                      // fused weight transpose
        int i = blockIdx.x * 256 + threadIdx.x; // 0..16383
        int k = i >> 7, n = i & 127;
        Wt[n * 128 + k] = f2b(W[k * 128 + n]);
    }
}

// ---- phase 2: per-bucket exclusive scan over the NP1 block columns ------
// One block per bucket row; in place; also emits the row total.
__global__ __launch_bounds__(256) void k_scanrow(int* __restrict__ hist,
                                                 int* __restrict__ btotal, int B) {
    __shared__ int s[256];
    const int b = blockIdx.x;
    const int t = threadIdx.x;
    int v0 = hist[b * NP1 + 2 * t];
    int v1 = hist[b * NP1 + 2 * t + 1];
    int pair = v0 + v1;
    s[t] = pair;
    __syncthreads();
    for (int off = 1; off < 256; off <<= 1) {
        int add = (t >= off) ? s[t - off] : 0;
        __syncthreads();
        s[t] += add;
        __syncthreads();
    }
    int exc = s[t] - pair;                      // exclusive prefix of this pair
    hist[b * NP1 + 2 * t]     = exc;
    hist[b * NP1 + 2 * t + 1] = exc + v0;
    if (t == 255) btotal[b] = s[255];
}

// ---- phase 3: bucket-grouped scatter (LDS cursors; in-block btotal scan) ----
__global__ __launch_bounds__(256) void k_scatter(const int* __restrict__ src,
                                                 const int* __restrict__ dst,
                                                 const int* __restrict__ hist,
                                                 const int* __restrict__ btotal,
                                                 unsigned* __restrict__ bucketed,
                                                 int E, int B, int chunk) {
    __shared__ int cur[MAXB];
    __shared__ int s[256];
    const int t = threadIdx.x;
    const int g = blockIdx.x;
    // exclusive scan of btotal (pairs), fused with cursor init
    int a0 = (2 * t     < B) ? btotal[2 * t]     : 0;
    int a1 = (2 * t + 1 < B) ? btotal[2 * t + 1] : 0;
    int pair = a0 + a1;
    s[t] = pair;
    __syncthreads();
    for (int off = 1; off < 256; off <<= 1) {
        int add = (t >= off) ? s[t - off] : 0;
        __syncthreads();
        s[t] += add;
        __syncthreads();
    }
    int ex = s[t] - pair;
    if (2 * t     < B) cur[2 * t]     = ex      + hist[(2 * t)     * NP1 + g];
    if (2 * t + 1 < B) cur[2 * t + 1] = ex + a0 + hist[(2 * t + 1) * NP1 + g];
    __syncthreads();
    int e0 = g * chunk;
    int e1 = min(E, e0 + chunk);
    for (int e = e0 + t; e < e1; e += 256) {
        int d = dst[e];
        int p = atomicAdd(&cur[d >> BSH], 1);   // LDS atomic
        bucketed[p] = (unsigned)src[e] | ((unsigned)(d & 255) << 17);
    }
}

// ---- phase 4: per-bucket CSR finalize (256 nodes/bucket) ----------------
__global__ __launch_bounds__(256) void k_csr(const unsigned* __restrict__ bucketed,
                                             const int* __restrict__ btotal,
                                             int* __restrict__ csr_src,
                                             int* __restrict__ rowptr,   // N+1
                                             float* __restrict__ dinv_g,
                                             int E, int B, int N) {
    const int b = blockIdx.x;
    const int t = threadIdx.x;
    __shared__ int sb[MAXB];
    __shared__ int s[256];
    __shared__ int sdeg[256], sscan[256], cur[256];
    // exclusive scan of btotal -> sb (bucket bases)
    int a0 = (2 * t     < B) ? btotal[2 * t]     : 0;
    int a1 = (2 * t + 1 < B) ? btotal[2 * t + 1] : 0;
    int pair = a0 + a1;
    s[t] = pair;
    sdeg[t] = 0;
    __syncthreads();
    for (int off = 1; off < 256; off <<= 1) {
        int add = (t >= off) ? s[t - off] : 0;
        __syncthreads();
        s[t] += add;
        __syncthreads();
    }
    int ex = s[t] - pair;
    if (2 * t     < B) sb[2 * t]     = ex;
    if (2 * t + 1 < B) sb[2 * t + 1] = ex + a0;
    __syncthreads();

    const int base = sb[b];
    const int cnt = btotal[b];
    const int node0 = b << BSH;

    for (int i = t; i < cnt; i += 256)
        atomicAdd(&sdeg[bucketed[base + i] >> 17], 1);
    __syncthreads();
    sscan[t] = sdeg[t];
    __syncthreads();
    for (int off = 1; off < 256; off <<= 1) {
        int add = (t >= off) ? sscan[t - off] : 0;
        __syncthreads();
        sscan[t] += add;
        __syncthreads();
    }
    {
        int rs = sscan[t] - sdeg[t];   // exclusive
        cur[t] = rs;
        int node = node0 + t;
        if (node < N) {
            rowptr[node] = base + rs;
            dinv_g[node] = rsqrtf((float)(sdeg[t] + 1));   // +1 self-loop
        }
    }
    if (b == B - 1 && t == 0) rowptr[N] = E;
    __syncthreads();
    for (int i = t; i < cnt; i += 256) {
        unsigned w = bucketed[base + i];
        int p = atomicAdd(&cur[w >> 17], 1);   // LDS atomic
        csr_src[base + p] = (int)(w & 0x1FFFFu);
    }
}

// ---- MFMA gemm: xs = bf16(dinv * (x @ W)), packed bf16x2 ----------------
// Grid is N/64 + 1 blocks: the last block's grow2==N lane-group writes the
// zeroed dummy row at index N (aggregate tail-gather target).
__global__ __launch_bounds__(256) void k_gemm(const float* __restrict__ x,
                                              const unsigned short* __restrict__ Wt,
                                              const float* __restrict__ dinv,
                                              unsigned* __restrict__ xs_out, int N) {
    __shared__ short out_lds[4][16][136];
    const int t = threadIdx.x;
    const int wv = t >> 6;
    const int lane = t & 63;
    const int quad = lane >> 4;
    const int lid = lane & 15;
    const int row0 = blockIdx.x * 64;

    int grow = row0 + wv * 16 + lid;
    int growc = grow < N ? grow : N - 1;
    short8 af[4];
#pragma unroll
    for (int q = 0; q < 4; ++q) {
        const float4* xr = (const float4*)(x + (size_t)growc * 128 + q * 32 + quad * 8);
        float4 f0 = xr[0], f1 = xr[1];
        af[q][0] = (short)f2b(f0.x); af[q][1] = (short)f2b(f0.y);
        af[q][2] = (short)f2b(f0.z); af[q][3] = (short)f2b(f0.w);
        af[q][4] = (short)f2b(f1.x); af[q][5] = (short)f2b(f1.y);
        af[q][6] = (short)f2b(f1.z); af[q][7] = (short)f2b(f1.w);
    }

    int drow = row0 + wv * 16 + quad * 4;
    float4 dv4;
    if (drow + 3 < N)      dv4 = *(const float4*)(dinv + drow);
    else {
        dv4.x = dinv[min(drow + 0, N - 1)];
        dv4.y = dinv[min(drow + 1, N - 1)];
        dv4.z = dinv[min(drow + 2, N - 1)];
        dv4.w = dinv[min(drow + 3, N - 1)];
    }

#pragma unroll
    for (int c = 0; c < 8; ++c) {
        f32x4 acc = {0.f, 0.f, 0.f, 0.f};
#pragma unroll
        for (int q = 0; q < 4; ++q) {
            const short8* bp = (const short8*)(Wt + (size_t)(c * 16 + lid) * 128 +
                                               q * 32 + quad * 8);
            acc = __builtin_amdgcn_mfma_f32_16x16x32_bf16(af[q], *bp, acc, 0, 0, 0);
        }
        out_lds[wv][quad * 4 + 0][c * 16 + lid] = (short)f2b(acc[0] * dv4.x);
        out_lds[wv][quad * 4 + 1][c * 16 + lid] = (short)f2b(acc[1] * dv4.y);
        out_lds[wv][quad * 4 + 2][c * 16 + lid] = (short)f2b(acc[2] * dv4.z);
        out_lds[wv][quad * 4 + 3][c * 16 + lid] = (short)f2b(acc[3] * dv4.w);
    }
    __syncthreads();

    int rl = lane >> 2;
    int cseg = lane & 3;
    int grow2 = row0 + wv * 16 + rl;
    if (grow2 <= N) {
        uint4* dstp = (uint4*)(xs_out + (size_t)grow2 * 64);
        if (grow2 < N) {
            const uint4* srcp = (const uint4*)((const char*)&out_lds[wv][rl][0] + cseg * 64);
#pragma unroll
            for (int tt = 0; tt < 4; ++tt) dstp[cseg * 4 + tt] = srcp[tt];
        } else {                                  // dummy zero row at index N
            uint4 z = make_uint4(0u, 0u, 0u, 0u);
#pragma unroll
            for (int tt = 0; tt < 4; ++tt) dstp[cseg * 4 + tt] = z;
        }
    }
}

// ---- aggregate: 4 nodes/wave, 16 lanes/node, 8 feats/lane ----------------
// [n_begin, n_end) node range per dispatch (2 halves this round).
__global__ __launch_bounds__(256) void k_aggregate(const uint4* __restrict__ xs4,
                                                   const int* __restrict__ csr_src,
                                                   const int* __restrict__ rowptr,
                                                   const float* __restrict__ dinv,
                                                   const float* __restrict__ bias,
                                                   float* __restrict__ out,
                                                   int N, int n_begin, int n_end) {
    const int t = threadIdx.x;
    const int lane = t & 63;
    const int sub = lane & 15;           // feature quarter: 8 floats (one uint4)
    const int gbase = lane & 48;         // 16-lane group base within wave
    const int n = n_begin + blockIdx.x * 16 + (t >> 4);
    if (n >= n_end) return;

    const int rs = rowptr[n];
    const int re = rowptr[n + 1];
    const float dv = dinv[n];
    const char* xb = (const char*)xs4;
    const unsigned subo = (unsigned)sub << 4;

    float4 a0 = make_float4(0.f, 0.f, 0.f, 0.f);
    float4 a1 = make_float4(0.f, 0.f, 0.f, 0.f);

    int idx = N;                                  // dummy zero row for tail slots
    if (rs + sub < re) idx = csr_src[rs + sub];

    for (int i0 = rs; i0 < re; i0 += 16) {
        const int idx_cur = idx;
        const int i1 = i0 + 16;
        idx = N;                                  // prefetch next round's index
        if (i1 + sub < re) idx = csr_src[i1 + sub];
        int m = re - i0; if (m > 16) m = 16;

        {   // slots 0..7: 8 gathers in flight
            int r0 = __shfl(idx_cur, gbase + 0);
            int r1 = __shfl(idx_cur, gbase + 1);
            int r2 = __shfl(idx_cur, gbase + 2);
            int r3 = __shfl(idx_cur, gbase + 3);
            int r4 = __shfl(idx_cur, gbase + 4);
            int r5 = __shfl(idx_cur, gbase + 5);
            int r6 = __shfl(idx_cur, gbase + 6);
            int r7 = __shfl(idx_cur, gbase + 7);
            uint4 u0 = *(const uint4*)(xb + ((((unsigned)r0) << 8) | subo));
            uint4 u1 = *(const uint4*)(xb + ((((unsigned)r1) << 8) | subo));
            uint4 u2 = *(const uint4*)(xb + ((((unsigned)r2) << 8) | subo));
            uint4 u3 = *(const uint4*)(xb + ((((unsigned)r3) << 8) | subo));
            uint4 u4 = *(const uint4*)(xb + ((((unsigned)r4) << 8) | subo));
            uint4 u5 = *(const uint4*)(xb + ((((unsigned)r5) << 8) | subo));
            uint4 u6 = *(const uint4*)(xb + ((((unsigned)r6) << 8) | subo));
            uint4 u7 = *(const uint4*)(xb + ((((unsigned)r7) << 8) | subo));
            acc4(a0, u0.x, u0.y); acc4(a1, u0.z, u0.w);
            acc4(a0, u1.x, u1.y); acc4(a1, u1.z, u1.w);
            acc4(a0, u2.x, u2.y); acc4(a1, u2.z, u2.w);
            acc4(a0, u3.x, u3.y); acc4(a1, u3.z, u3.w);
            acc4(a0, u4.x, u4.y); acc4(a1, u4.z, u4.w);
            acc4(a0, u5.x, u5.y); acc4(a1, u5.z, u5.w);
            acc4(a0, u6.x, u6.y); acc4(a1, u6.z, u6.w);
            acc4(a0, u7.x, u7.y); acc4(a1, u7.z, u7.w);
        }
        if (m > 8) {   // slots 8..15
            int r0 = __shfl(idx_cur, gbase + 8);
            int r1 = __shfl(idx_cur, gbase + 9);
            int r2 = __shfl(idx_cur, gbase + 10);
            int r3 = __shfl(idx_cur, gbase + 11);
            int r4 = __shfl(idx_cur, gbase + 12);
            int r5 = __shfl(idx_cur, gbase + 13);
            int r6 = __shfl(idx_cur, gbase + 14);
            int r7 = __shfl(idx_cur, gbase + 15);
            uint4 u0 = *(const uint4*)(xb + ((((unsigned)r0) << 8) | subo));
            uint4 u1 = *(const uint4*)(xb + ((((unsigned)r1) << 8) | subo));
            uint4 u2 = *(const uint4*)(xb + ((((unsigned)r2) << 8) | subo));
            uint4 u3 = *(const uint4*)(xb + ((((unsigned)r3) << 8) | subo));
            uint4 u4 = *(const uint4*)(xb + ((((unsigned)r4) << 8) | subo));
            uint4 u5 = *(const uint4*)(xb + ((((unsigned)r5) << 8) | subo));
            uint4 u6 = *(const uint4*)(xb + ((((unsigned)r6) << 8) | subo));
            uint4 u7 = *(const uint4*)(xb + ((((unsigned)r7) << 8) | subo));
            acc4(a0, u0.x, u0.y); acc4(a1, u0.z, u0.w);
            acc4(a0, u1.x, u1.y); acc4(a1, u1.z, u1.w);
            acc4(a0, u2.x, u2.y); acc4(a1, u2.z, u2.w);
            acc4(a0, u3.x, u3.y); acc4(a1, u3.z, u3.w);
            acc4(a0, u4.x, u4.y); acc4(a1, u4.z, u4.w);
            acc4(a0, u5.x, u5.y); acc4(a1, u5.z, u5.w);
            acc4(a0, u6.x, u6.y); acc4(a1, u6.z, u6.w);
            acc4(a0, u7.x, u7.y); acc4(a1, u7.z, u7.w);
        }
    }

    // self-loop (xs row n already dinv[n]-scaled)
    uint4 su = *(const uint4*)(xb + ((((unsigned)n) << 8) | subo));
    acc4(a0, su.x, su.y);
    acc4(a1, su.z, su.w);

    const float4* bp = (const float4*)bias;
    float4 b0 = bp[sub * 2];
    float4 b1 = bp[sub * 2 + 1];
    f32x4 o0, o1;
    o0[0] = fmaxf(dv * a0.x + b0.x, 0.f);
    o0[1] = fmaxf(dv * a0.y + b0.y, 0.f);
    o0[2] = fmaxf(dv * a0.z + b0.z, 0.f);
    o0[3] = fmaxf(dv * a0.w + b0.w, 0.f);
    o1[0] = fmaxf(dv * a1.x + b1.x, 0.f);
    o1[1] = fmaxf(dv * a1.y + b1.y, 0.f);
    o1[2] = fmaxf(dv * a1.z + b1.z, 0.f);
    o1[3] = fmaxf(dv * a1.w + b1.w, 0.f);

    f32x4* op = (f32x4*)(out + (size_t)n * 128 + sub * 8);
    __builtin_nontemporal_store(o0, op);          // out is write-once: don't
    __builtin_nontemporal_store(o1, op + 1);      // evict xs gather lines
}

extern "C" void kernel_launch(void* const* d_in, const int* in_sizes, int n_in,
                              void* d_out, int out_size, void* d_ws, size_t ws_size,
                              hipStream_t stream) {
    const float* x   = (const float*)d_in[0];
    const int*   ei  = (const int*)d_in[1];     // [2, E] flat: src then dst
    const float* W   = (const float*)d_in[2];
    const float* b   = (const float*)d_in[3];
    float*       out = (float*)d_out;

    const int N = in_sizes[0] / 128;
    const int E = in_sizes[1] / 2;
    const int* src = ei;
    const int* dst = ei + E;

    const int B = (N + 255) >> BSH;          // 392 buckets (<= MAXB)
    const int M = B * NP1;                   // hist entries
    const int chunk = (E + NP1 - 1) / NP1;   // edges per phase-1 block

    // workspace carve (256B aligned)
    auto align = [](size_t v) { return (v + 255) & ~(size_t)255; };
    char* p = (char*)d_ws;
    int*            hist     = (int*)p;            p += align((size_t)M * 4);
    int*            btotal   = (int*)p;            p += align((size_t)B * 4);
    int*            rowptr   = (int*)p;            p += align(((size_t)N + 1) * 4);
    float*          dinv     = (float*)p;          p += align((size_t)N * 4);
    unsigned*       bucketed = (unsigned*)p;       p += align((size_t)E * 4);
    int*            csr_src  = (int*)p;            p += align((size_t)E * 4);
    unsigned*       xs       = (unsigned*)p;       p += align(((size_t)N + 1) * 64 * 4);
    unsigned short* Wt       = (unsigned short*)p; p += align(128 * 128 * 2);
    (void)ws_size;

    k_hist    <<<NP1, 256, 0, stream>>>(dst, hist, W, Wt, E, B, chunk);
    k_scanrow <<<B, 256, 0, stream>>>(hist, btotal, B);
    k_scatter <<<NP1, 256, 0, stream>>>(src, dst, hist, btotal, bucketed, E, B, chunk);
    k_csr     <<<B, 256, 0, stream>>>(bucketed, btotal, csr_src, rowptr,
                                      dinv, E, B, N);
    k_gemm    <<<N / 64 + 1, 256, 0, stream>>>(x, Wt, dinv, xs, N);   // +1: dummy row N

    // aggregate in 2 halves (keeps 41us fills visible; any >41us kernel surfaces)
    const int q = (N + 1) / 2;
    for (int i = 0; i < 2; ++i) {
        int n0 = i * q;
        int n1 = min(N, n0 + q);
        if (n0 >= n1) break;
        int blocks = (n1 - n0 + 15) / 16;
        k_aggregate<<<blocks, 256, 0, stream>>>((const uint4*)xs, csr_src, rowptr,
                                                dinv, b, out, N, n0, n1);
    }
}

// Round 10
// 238.455 us; speedup vs baseline: 1.0848x; 1.0338x over previous
//
#include <hip/hip_runtime.h>
#include <hip/hip_bf16.h>

// GCNConv: out = relu( D^{-1/2} (A + I) D^{-1/2} (x @ W) + b )
// CSR build via atomic-free two-phase bucket sort (bucket = dst>>8, 256 nodes):
//   1. k_hist   : per-block LDS histograms -> hist[bucket][block] (+ Wt convert)
//   2. k_scanrow: per-bucket exclusive scan of the 512 block columns (+ btotal)
//   3. k_scatter: edges -> bucket-grouped packed array (src | dlow<<17)
//   4. k_csr    : per-bucket LDS hist+scan+rank -> csr_src, rowptr[N+1], dinv
//   5. k_gemm   : xs = bf16( dinv[n] * (x[n] @ W) ) via MFMA 16x16x32 bf16.
//                 ROUND 10: 2 row-tiles per wave — each Wt fragment loaded once
//                 feeds 2 MFMAs. Round-8 analysis: 44us = 105k cyc vs 8us BW
//                 floor; cost = per-tile re-stream of the full 32KB Wt (L1-sized,
//                 thrashed by x/xs traffic) -> ~200cy L2 chain per MFMA. Reuse
//                 halves that + doubles ILP. No barrier (out_lds wave-private).
//                 Plain grid (persistent loop of round 9 dropped: container
//                 failed; structure unproven under this harness).
//   6. k_aggregate: 4 nodes/wave, 8 gathers in flight, csr prefetch, NT stores
//                 (2 halves: keeps the 41us harness fills visible in top-5)
// Harness rules: NO cooperative launch, NO inter-block spin (graph capture).
// Harness poisons the 256MiB workspace every iteration (41us fill) — floor.

#define NP1 512          // blocks in phase-1 (hist/scatter): 2 per CU
#define BSH 8            // bucket shift: 256 nodes per bucket
#define MAXB 512         // bucket count cap (N <= 131072)

typedef short  short8 __attribute__((ext_vector_type(8)));
typedef float  f32x4  __attribute__((ext_vector_type(4)));

__device__ inline unsigned short f2b(float f) {   // fp32 -> bf16 RNE
    unsigned u = __float_as_uint(f);
    return (unsigned short)((u + 0x7fffu + ((u >> 16) & 1u)) >> 16);
}

__device__ inline void acc4(float4& a, unsigned lo, unsigned hi) {
    a.x += __uint_as_float(lo << 16);
    a.y += __uint_as_float(lo & 0xffff0000u);
    a.z += __uint_as_float(hi << 16);
    a.w += __uint_as_float(hi & 0xffff0000u);
}

// ---- phase 1: bucket histogram (+ fused Wt = bf16(W^T)) -----------------
__global__ __launch_bounds__(256) void k_hist(const int* __restrict__ dst,
                                              int* __restrict__ hist,
                                              const float* __restrict__ W,
                                              unsigned short* __restrict__ Wt,
                                              int E, int B, int chunk) {
    __shared__ int h[MAXB];
    for (int i = threadIdx.x; i < B; i += 256) h[i] = 0;
    __syncthreads();
    int e0 = blockIdx.x * chunk;
    int e1 = min(E, e0 + chunk);
    for (int e = e0 + threadIdx.x; e < e1; e += 256)
        atomicAdd(&h[dst[e] >> BSH], 1);
    __syncthreads();
    for (int i = threadIdx.x; i < B; i += 256)
        hist[i * NP1 + blockIdx.x] = h[i];
    if (blockIdx.x < 64) {                      // fused weight transpose
        int i = blockIdx.x * 256 + threadIdx.x; // 0..16383
        int k = i >> 7, n = i & 127;
        Wt[n * 128 + k] = f2b(W[k * 128 + n]);
    }
}

// ---- phase 2: per-bucket exclusive scan over the NP1 block columns ------
__global__ __launch_bounds__(256) void k_scanrow(int* __restrict__ hist,
                                                 int* __restrict__ btotal, int B) {
    __shared__ int s[256];
    const int b = blockIdx.x;
    const int t = threadIdx.x;
    int v0 = hist[b * NP1 + 2 * t];
    int v1 = hist[b * NP1 + 2 * t + 1];
    int pair = v0 + v1;
    s[t] = pair;
    __syncthreads();
    for (int off = 1; off < 256; off <<= 1) {
        int add = (t >= off) ? s[t - off] : 0;
        __syncthreads();
        s[t] += add;
        __syncthreads();
    }
    int exc = s[t] - pair;                      // exclusive prefix of this pair
    hist[b * NP1 + 2 * t]     = exc;
    hist[b * NP1 + 2 * t + 1] = exc + v0;
    if (t == 255) btotal[b] = s[255];
}

// ---- phase 3: bucket-grouped scatter (LDS cursors; in-block btotal scan) ----
__global__ __launch_bounds__(256) void k_scatter(const int* __restrict__ src,
                                                 const int* __restrict__ dst,
                                                 const int* __restrict__ hist,
                                                 const int* __restrict__ btotal,
                                                 unsigned* __restrict__ bucketed,
                                                 int E, int B, int chunk) {
    __shared__ int cur[MAXB];
    __shared__ int s[256];
    const int t = threadIdx.x;
    const int g = blockIdx.x;
    // exclusive scan of btotal (pairs), fused with cursor init
    int a0 = (2 * t     < B) ? btotal[2 * t]     : 0;
    int a1 = (2 * t + 1 < B) ? btotal[2 * t + 1] : 0;
    int pair = a0 + a1;
    s[t] = pair;
    __syncthreads();
    for (int off = 1; off < 256; off <<= 1) {
        int add = (t >= off) ? s[t - off] : 0;
        __syncthreads();
        s[t] += add;
        __syncthreads();
    }
    int ex = s[t] - pair;
    if (2 * t     < B) cur[2 * t]     = ex      + hist[(2 * t)     * NP1 + g];
    if (2 * t + 1 < B) cur[2 * t + 1] = ex + a0 + hist[(2 * t + 1) * NP1 + g];
    __syncthreads();
    int e0 = g * chunk;
    int e1 = min(E, e0 + chunk);
    for (int e = e0 + t; e < e1; e += 256) {
        int d = dst[e];
        int p = atomicAdd(&cur[d >> BSH], 1);   // LDS atomic
        bucketed[p] = (unsigned)src[e] | ((unsigned)(d & 255) << 17);
    }
}

// ---- phase 4: per-bucket CSR finalize (256 nodes/bucket) ----------------
__global__ __launch_bounds__(256) void k_csr(const unsigned* __restrict__ bucketed,
                                             const int* __restrict__ btotal,
                                             int* __restrict__ csr_src,
                                             int* __restrict__ rowptr,   // N+1
                                             float* __restrict__ dinv_g,
                                             int E, int B, int N) {
    const int b = blockIdx.x;
    const int t = threadIdx.x;
    __shared__ int sb[MAXB];
    __shared__ int s[256];
    __shared__ int sdeg[256], sscan[256], cur[256];
    // exclusive scan of btotal -> sb (bucket bases)
    int a0 = (2 * t     < B) ? btotal[2 * t]     : 0;
    int a1 = (2 * t + 1 < B) ? btotal[2 * t + 1] : 0;
    int pair = a0 + a1;
    s[t] = pair;
    sdeg[t] = 0;
    __syncthreads();
    for (int off = 1; off < 256; off <<= 1) {
        int add = (t >= off) ? s[t - off] : 0;
        __syncthreads();
        s[t] += add;
        __syncthreads();
    }
    int ex = s[t] - pair;
    if (2 * t     < B) sb[2 * t]     = ex;
    if (2 * t + 1 < B) sb[2 * t + 1] = ex + a0;
    __syncthreads();

    const int base = sb[b];
    const int cnt = btotal[b];
    const int node0 = b << BSH;

    for (int i = t; i < cnt; i += 256)
        atomicAdd(&sdeg[bucketed[base + i] >> 17], 1);
    __syncthreads();
    sscan[t] = sdeg[t];
    __syncthreads();
    for (int off = 1; off < 256; off <<= 1) {
        int add = (t >= off) ? sscan[t - off] : 0;
        __syncthreads();
        sscan[t] += add;
        __syncthreads();
    }
    {
        int rs = sscan[t] - sdeg[t];   // exclusive
        cur[t] = rs;
        int node = node0 + t;
        if (node < N) {
            rowptr[node] = base + rs;
            dinv_g[node] = rsqrtf((float)(sdeg[t] + 1));   // +1 self-loop
        }
    }
    if (b == B - 1 && t == 0) rowptr[N] = E;
    __syncthreads();
    for (int i = t; i < cnt; i += 256) {
        unsigned w = bucketed[base + i];
        int p = atomicAdd(&cur[w >> 17], 1);   // LDS atomic
        csr_src[base + p] = (int)(w & 0x1FFFFu);
    }
}

// ---- MFMA gemm: xs = bf16(dinv * (x @ W)), packed bf16x2 ----------------
// 2 row-tiles per wave (B-fragment reuse x2), 128 rows/block, no barrier
// (out_lds strictly wave-indexed). Grid (N+128)>>7 covers dummy row N: the
// grow2==N lane-group writes the zeroed dummy row (aggregate tail target).
__global__ __launch_bounds__(256) void k_gemm(const float* __restrict__ x,
                                              const unsigned short* __restrict__ Wt,
                                              const float* __restrict__ dinv,
                                              unsigned* __restrict__ xs_out, int N) {
    __shared__ short out_lds[8][16][136];       // [wv*2+tile][row][col]
    const int t = threadIdx.x;
    const int wv = t >> 6;
    const int lane = t & 63;
    const int quad = lane >> 4;
    const int lid = lane & 15;
    const int row0 = blockIdx.x * 128 + wv * 32;   // this wave's 32 rows

    short8 af0[4], af1[4];
    {   // load + convert tile 0 (rows row0+lid) and tile 1 (rows row0+16+lid)
        int r0 = row0 + lid;       int r0c = r0 < N ? r0 : N - 1;
        int r1 = row0 + 16 + lid;  int r1c = r1 < N ? r1 : N - 1;
#pragma unroll
        for (int q = 0; q < 4; ++q) {
            const float4* xr0 = (const float4*)(x + (size_t)r0c * 128 + q * 32 + quad * 8);
            const float4* xr1 = (const float4*)(x + (size_t)r1c * 128 + q * 32 + quad * 8);
            float4 f0 = xr0[0], f1 = xr0[1];
            float4 g0 = xr1[0], g1 = xr1[1];
            af0[q][0] = (short)f2b(f0.x); af0[q][1] = (short)f2b(f0.y);
            af0[q][2] = (short)f2b(f0.z); af0[q][3] = (short)f2b(f0.w);
            af0[q][4] = (short)f2b(f1.x); af0[q][5] = (short)f2b(f1.y);
            af0[q][6] = (short)f2b(f1.z); af0[q][7] = (short)f2b(f1.w);
            af1[q][0] = (short)f2b(g0.x); af1[q][1] = (short)f2b(g0.y);
            af1[q][2] = (short)f2b(g0.z); af1[q][3] = (short)f2b(g0.w);
            af1[q][4] = (short)f2b(g1.x); af1[q][5] = (short)f2b(g1.y);
            af1[q][6] = (short)f2b(g1.z); af1[q][7] = (short)f2b(g1.w);
        }
    }

    float4 dv0, dv1;
    {
        int dr0 = row0 + quad * 4;
        int dr1 = row0 + 16 + quad * 4;
        if (dr0 + 3 < N) dv0 = *(const float4*)(dinv + dr0);
        else {
            dv0.x = dinv[min(dr0 + 0, N - 1)];
            dv0.y = dinv[min(dr0 + 1, N - 1)];
            dv0.z = dinv[min(dr0 + 2, N - 1)];
            dv0.w = dinv[min(dr0 + 3, N - 1)];
        }
        if (dr1 + 3 < N) dv1 = *(const float4*)(dinv + dr1);
        else {
            dv1.x = dinv[min(dr1 + 0, N - 1)];
            dv1.y = dinv[min(dr1 + 1, N - 1)];
            dv1.z = dinv[min(dr1 + 2, N - 1)];
            dv1.w = dinv[min(dr1 + 3, N - 1)];
        }
    }

#pragma unroll
    for (int c = 0; c < 8; ++c) {
        f32x4 a0 = {0.f, 0.f, 0.f, 0.f};
        f32x4 a1 = {0.f, 0.f, 0.f, 0.f};
#pragma unroll
        for (int q = 0; q < 4; ++q) {
            short8 bq = *(const short8*)(Wt + (size_t)(c * 16 + lid) * 128 +
                                         q * 32 + quad * 8);
            a0 = __builtin_amdgcn_mfma_f32_16x16x32_bf16(af0[q], bq, a0, 0, 0, 0);
            a1 = __builtin_amdgcn_mfma_f32_16x16x32_bf16(af1[q], bq, a1, 0, 0, 0);
        }
        const int sb = wv * 2;
        out_lds[sb + 0][quad * 4 + 0][c * 16 + lid] = (short)f2b(a0[0] * dv0.x);
        out_lds[sb + 0][quad * 4 + 1][c * 16 + lid] = (short)f2b(a0[1] * dv0.y);
        out_lds[sb + 0][quad * 4 + 2][c * 16 + lid] = (short)f2b(a0[2] * dv0.z);
        out_lds[sb + 0][quad * 4 + 3][c * 16 + lid] = (short)f2b(a0[3] * dv0.w);
        out_lds[sb + 1][quad * 4 + 0][c * 16 + lid] = (short)f2b(a1[0] * dv1.x);
        out_lds[sb + 1][quad * 4 + 1][c * 16 + lid] = (short)f2b(a1[1] * dv1.y);
        out_lds[sb + 1][quad * 4 + 2][c * 16 + lid] = (short)f2b(a1[2] * dv1.z);
        out_lds[sb + 1][quad * 4 + 3][c * 16 + lid] = (short)f2b(a1[3] * dv1.w);
    }
    // no __syncthreads: out_lds[wv*2+tl] is written and read only by wave wv

    const int rl = lane >> 2;
    const int cseg = lane & 3;
#pragma unroll
    for (int tl = 0; tl < 2; ++tl) {
        int grow2 = row0 + tl * 16 + rl;
        if (grow2 <= N) {
            uint4* dstp = (uint4*)(xs_out + (size_t)grow2 * 64);
            if (grow2 < N) {
                const uint4* srcp = (const uint4*)((const char*)&out_lds[wv * 2 + tl][rl][0] + cseg * 64);
#pragma unroll
                for (int tt = 0; tt < 4; ++tt) dstp[cseg * 4 + tt] = srcp[tt];
            } else {                              // dummy zero row at index N
                uint4 z = make_uint4(0u, 0u, 0u, 0u);
#pragma unroll
                for (int tt = 0; tt < 4; ++tt) dstp[cseg * 4 + tt] = z;
            }
        }
    }
}

// ---- aggregate: 4 nodes/wave, 16 lanes/node, 8 feats/lane ----------------
// [n_begin, n_end) node range per dispatch (2 halves for profile visibility).
__global__ __launch_bounds__(256) void k_aggregate(const uint4* __restrict__ xs4,
                                                   const int* __restrict__ csr_src,
                                                   const int* __restrict__ rowptr,
                                                   const float* __restrict__ dinv,
                                                   const float* __restrict__ bias,
                                                   float* __restrict__ out,
                                                   int N, int n_begin, int n_end) {
    const int t = threadIdx.x;
    const int lane = t & 63;
    const int sub = lane & 15;           // feature quarter: 8 floats (one uint4)
    const int gbase = lane & 48;         // 16-lane group base within wave
    const int n = n_begin + blockIdx.x * 16 + (t >> 4);
    if (n >= n_end) return;

    const int rs = rowptr[n];
    const int re = rowptr[n + 1];
    const float dv = dinv[n];
    const char* xb = (const char*)xs4;
    const unsigned subo = (unsigned)sub << 4;

    float4 a0 = make_float4(0.f, 0.f, 0.f, 0.f);
    float4 a1 = make_float4(0.f, 0.f, 0.f, 0.f);

    int idx = N;                                  // dummy zero row for tail slots
    if (rs + sub < re) idx = csr_src[rs + sub];

    for (int i0 = rs; i0 < re; i0 += 16) {
        const int idx_cur = idx;
        const int i1 = i0 + 16;
        idx = N;                                  // prefetch next round's index
        if (i1 + sub < re) idx = csr_src[i1 + sub];
        int m = re - i0; if (m > 16) m = 16;

        {   // slots 0..7: 8 gathers in flight
            int r0 = __shfl(idx_cur, gbase + 0);
            int r1 = __shfl(idx_cur, gbase + 1);
            int r2 = __shfl(idx_cur, gbase + 2);
            int r3 = __shfl(idx_cur, gbase + 3);
            int r4 = __shfl(idx_cur, gbase + 4);
            int r5 = __shfl(idx_cur, gbase + 5);
            int r6 = __shfl(idx_cur, gbase + 6);
            int r7 = __shfl(idx_cur, gbase + 7);
            uint4 u0 = *(const uint4*)(xb + ((((unsigned)r0) << 8) | subo));
            uint4 u1 = *(const uint4*)(xb + ((((unsigned)r1) << 8) | subo));
            uint4 u2 = *(const uint4*)(xb + ((((unsigned)r2) << 8) | subo));
            uint4 u3 = *(const uint4*)(xb + ((((unsigned)r3) << 8) | subo));
            uint4 u4 = *(const uint4*)(xb + ((((unsigned)r4) << 8) | subo));
            uint4 u5 = *(const uint4*)(xb + ((((unsigned)r5) << 8) | subo));
            uint4 u6 = *(const uint4*)(xb + ((((unsigned)r6) << 8) | subo));
            uint4 u7 = *(const uint4*)(xb + ((((unsigned)r7) << 8) | subo));
            acc4(a0, u0.x, u0.y); acc4(a1, u0.z, u0.w);
            acc4(a0, u1.x, u1.y); acc4(a1, u1.z, u1.w);
            acc4(a0, u2.x, u2.y); acc4(a1, u2.z, u2.w);
            acc4(a0, u3.x, u3.y); acc4(a1, u3.z, u3.w);
            acc4(a0, u4.x, u4.y); acc4(a1, u4.z, u4.w);
            acc4(a0, u5.x, u5.y); acc4(a1, u5.z, u5.w);
            acc4(a0, u6.x, u6.y); acc4(a1, u6.z, u6.w);
            acc4(a0, u7.x, u7.y); acc4(a1, u7.z, u7.w);
        }
        if (m > 8) {   // slots 8..15
            int r0 = __shfl(idx_cur, gbase + 8);
            int r1 = __shfl(idx_cur, gbase + 9);
            int r2 = __shfl(idx_cur, gbase + 10);
            int r3 = __shfl(idx_cur, gbase + 11);
            int r4 = __shfl(idx_cur, gbase + 12);
            int r5 = __shfl(idx_cur, gbase + 13);
            int r6 = __shfl(idx_cur, gbase + 14);
            int r7 = __shfl(idx_cur, gbase + 15);
            uint4 u0 = *(const uint4*)(xb + ((((unsigned)r0) << 8) | subo));
            uint4 u1 = *(const uint4*)(xb + ((((unsigned)r1) << 8) | subo));
            uint4 u2 = *(const uint4*)(xb + ((((unsigned)r2) << 8) | subo));
            uint4 u3 = *(const uint4*)(xb + ((((unsigned)r3) << 8) | subo));
            uint4 u4 = *(const uint4*)(xb + ((((unsigned)r4) << 8) | subo));
            uint4 u5 = *(const uint4*)(xb + ((((unsigned)r5) << 8) | subo));
            uint4 u6 = *(const uint4*)(xb + ((((unsigned)r6) << 8) | subo));
            uint4 u7 = *(const uint4*)(xb + ((((unsigned)r7) << 8) | subo));
            acc4(a0, u0.x, u0.y); acc4(a1, u0.z, u0.w);
            acc4(a0, u1.x, u1.y); acc4(a1, u1.z, u1.w);
            acc4(a0, u2.x, u2.y); acc4(a1, u2.z, u2.w);
            acc4(a0, u3.x, u3.y); acc4(a1, u3.z, u3.w);
            acc4(a0, u4.x, u4.y); acc4(a1, u4.z, u4.w);
            acc4(a0, u5.x, u5.y); acc4(a1, u5.z, u5.w);
            acc4(a0, u6.x, u6.y); acc4(a1, u6.z, u6.w);
            acc4(a0, u7.x, u7.y); acc4(a1, u7.z, u7.w);
        }
    }

    // self-loop (xs row n already dinv[n]-scaled)
    uint4 su = *(const uint4*)(xb + ((((unsigned)n) << 8) | subo));
    acc4(a0, su.x, su.y);
    acc4(a1, su.z, su.w);

    const float4* bp = (const float4*)bias;
    float4 b0 = bp[sub * 2];
    float4 b1 = bp[sub * 2 + 1];
    f32x4 o0, o1;
    o0[0] = fmaxf(dv * a0.x + b0.x, 0.f);
    o0[1] = fmaxf(dv * a0.y + b0.y, 0.f);
    o0[2] = fmaxf(dv * a0.z + b0.z, 0.f);
    o0[3] = fmaxf(dv * a0.w + b0.w, 0.f);
    o1[0] = fmaxf(dv * a1.x + b1.x, 0.f);
    o1[1] = fmaxf(dv * a1.y + b1.y, 0.f);
    o1[2] = fmaxf(dv * a1.z + b1.z, 0.f);
    o1[3] = fmaxf(dv * a1.w + b1.w, 0.f);

    f32x4* op = (f32x4*)(out + (size_t)n * 128 + sub * 8);
    __builtin_nontemporal_store(o0, op);          // out is write-once: don't
    __builtin_nontemporal_store(o1, op + 1);      // evict xs gather lines
}

extern "C" void kernel_launch(void* const* d_in, const int* in_sizes, int n_in,
                              void* d_out, int out_size, void* d_ws, size_t ws_size,
                              hipStream_t stream) {
    const float* x   = (const float*)d_in[0];
    const int*   ei  = (const int*)d_in[1];     // [2, E] flat: src then dst
    const float* W   = (const float*)d_in[2];
    const float* b   = (const float*)d_in[3];
    float*       out = (float*)d_out;

    const int N = in_sizes[0] / 128;
    const int E = in_sizes[1] / 2;
    const int* src = ei;
    const int* dst = ei + E;

    const int B = (N + 255) >> BSH;          // 392 buckets (<= MAXB)
    const int M = B * NP1;                   // hist entries
    const int chunk = (E + NP1 - 1) / NP1;   // edges per phase-1 block

    // workspace carve (256B aligned)
    auto align = [](size_t v) { return (v + 255) & ~(size_t)255; };
    char* p = (char*)d_ws;
    int*            hist     = (int*)p;            p += align((size_t)M * 4);
    int*            btotal   = (int*)p;            p += align((size_t)B * 4);
    int*            rowptr   = (int*)p;            p += align(((size_t)N + 1) * 4);
    float*          dinv     = (float*)p;          p += align((size_t)N * 4);
    unsigned*       bucketed = (unsigned*)p;       p += align((size_t)E * 4);
    int*            csr_src  = (int*)p;            p += align((size_t)E * 4);
    unsigned*       xs       = (unsigned*)p;       p += align(((size_t)N + 1) * 64 * 4);
    unsigned short* Wt       = (unsigned short*)p; p += align(128 * 128 * 2);
    (void)ws_size;

    k_hist    <<<NP1, 256, 0, stream>>>(dst, hist, W, Wt, E, B, chunk);
    k_scanrow <<<B, 256, 0, stream>>>(hist, btotal, B);
    k_scatter <<<NP1, 256, 0, stream>>>(src, dst, hist, btotal, bucketed, E, B, chunk);
    k_csr     <<<B, 256, 0, stream>>>(bucketed, btotal, csr_src, rowptr,
                                      dinv, E, B, N);
    k_gemm    <<<(N + 128) >> 7, 256, 0, stream>>>(x, Wt, dinv, xs, N);  // covers row N

    // aggregate in 2 halves (keeps 41us fills visible; any >41us kernel surfaces)
    const int q = (N + 1) / 2;
    for (int i = 0; i < 2; ++i) {
        int n0 = i * q;
        int n1 = min(N, n0 + q);
        if (n0 >= n1) break;
        int blocks = (n1 - n0 + 15) / 16;
        k_aggregate<<<blocks, 256, 0, stream>>>((const uint4*)xs, csr_src, rowptr,
                                                dinv, b, out, N, n0, n1);
    }
}

// Round 11
// 225.254 us; speedup vs baseline: 1.1484x; 1.0586x over previous
//
#include <hip/hip_runtime.h>
#include <hip/hip_bf16.h>

// GCNConv: out = relu( D^{-1/2} (A + I) D^{-1/2} (x @ W) + b )
// CSR build via atomic-free two-phase bucket sort (bucket = dst>>8, 256 nodes):
//   1. k_hist   : per-block LDS histograms -> hist[bucket][block] (+ Wt convert)
//   2. k_scanrow: per-bucket exclusive scan of the 512 block columns (+ btotal)
//   3. k_scatter: edges -> bucket-grouped packed array (src | dlow<<17)
//   4. k_csr    : per-bucket LDS hist+scan+rank -> csr_src, rowptr[N+1], dinv
//   5. k_gemm   : xs = bf16( dinv[n] * (x[n] @ W) ) via MFMA 16x16x32 bf16.
//                 ROUND 11: Wt staged once per block into LDS with XOR swizzle
//                 (chunk c16 stored at c16^(row&7): 64-lane b128 read lands
//                 uniformly 8 accesses/bank = b128 minimum, conflict-free).
//                 Kills the per-wave 32KB Wt re-stream from L2 (round-8
//                 diagnosis: L1-thrashed Wt -> ~200cy L2 chain per MFMA).
//                 x loads issued before the staging barrier. 2-tile B reuse
//                 kept. out_lds wave-private (no second barrier).
//   6. k_aggregate: 4 nodes/wave, 8 gathers in flight, csr prefetch, NT stores
//                 (back to ONE dispatch — visibility split no longer needed)
// Harness rules: NO cooperative launch, NO inter-block spin (graph capture).
// Harness poisons the 256MiB workspace every iteration (41us fill) — floor.

#define NP1 512          // blocks in phase-1 (hist/scatter): 2 per CU
#define BSH 8            // bucket shift: 256 nodes per bucket
#define MAXB 512         // bucket count cap (N <= 131072)

typedef short  short8 __attribute__((ext_vector_type(8)));
typedef float  f32x4  __attribute__((ext_vector_type(4)));

__device__ inline unsigned short f2b(float f) {   // fp32 -> bf16 RNE
    unsigned u = __float_as_uint(f);
    return (unsigned short)((u + 0x7fffu + ((u >> 16) & 1u)) >> 16);
}

__device__ inline void acc4(float4& a, unsigned lo, unsigned hi) {
    a.x += __uint_as_float(lo << 16);
    a.y += __uint_as_float(lo & 0xffff0000u);
    a.z += __uint_as_float(hi << 16);
    a.w += __uint_as_float(hi & 0xffff0000u);
}

// ---- phase 1: bucket histogram (+ fused Wt = bf16(W^T)) -----------------
__global__ __launch_bounds__(256) void k_hist(const int* __restrict__ dst,
                                              int* __restrict__ hist,
                                              const float* __restrict__ W,
                                              unsigned short* __restrict__ Wt,
                                              int E, int B, int chunk) {
    __shared__ int h[MAXB];
    for (int i = threadIdx.x; i < B; i += 256) h[i] = 0;
    __syncthreads();
    int e0 = blockIdx.x * chunk;
    int e1 = min(E, e0 + chunk);
    for (int e = e0 + threadIdx.x; e < e1; e += 256)
        atomicAdd(&h[dst[e] >> BSH], 1);
    __syncthreads();
    for (int i = threadIdx.x; i < B; i += 256)
        hist[i * NP1 + blockIdx.x] = h[i];
    if (blockIdx.x < 64) {                      // fused weight transpose
        int i = blockIdx.x * 256 + threadIdx.x; // 0..16383
        int k = i >> 7, n = i & 127;
        Wt[n * 128 + k] = f2b(W[k * 128 + n]);
    }
}

// ---- phase 2: per-bucket exclusive scan over the NP1 block columns ------
__global__ __launch_bounds__(256) void k_scanrow(int* __restrict__ hist,
                                                 int* __restrict__ btotal, int B) {
    __shared__ int s[256];
    const int b = blockIdx.x;
    const int t = threadIdx.x;
    int v0 = hist[b * NP1 + 2 * t];
    int v1 = hist[b * NP1 + 2 * t + 1];
    int pair = v0 + v1;
    s[t] = pair;
    __syncthreads();
    for (int off = 1; off < 256; off <<= 1) {
        int add = (t >= off) ? s[t - off] : 0;
        __syncthreads();
        s[t] += add;
        __syncthreads();
    }
    int exc = s[t] - pair;                      // exclusive prefix of this pair
    hist[b * NP1 + 2 * t]     = exc;
    hist[b * NP1 + 2 * t + 1] = exc + v0;
    if (t == 255) btotal[b] = s[255];
}

// ---- phase 3: bucket-grouped scatter (LDS cursors; in-block btotal scan) ----
__global__ __launch_bounds__(256) void k_scatter(const int* __restrict__ src,
                                                 const int* __restrict__ dst,
                                                 const int* __restrict__ hist,
                                                 const int* __restrict__ btotal,
                                                 unsigned* __restrict__ bucketed,
                                                 int E, int B, int chunk) {
    __shared__ int cur[MAXB];
    __shared__ int s[256];
    const int t = threadIdx.x;
    const int g = blockIdx.x;
    // exclusive scan of btotal (pairs), fused with cursor init
    int a0 = (2 * t     < B) ? btotal[2 * t]     : 0;
    int a1 = (2 * t + 1 < B) ? btotal[2 * t + 1] : 0;
    int pair = a0 + a1;
    s[t] = pair;
    __syncthreads();
    for (int off = 1; off < 256; off <<= 1) {
        int add = (t >= off) ? s[t - off] : 0;
        __syncthreads();
        s[t] += add;
        __syncthreads();
    }
    int ex = s[t] - pair;
    if (2 * t     < B) cur[2 * t]     = ex      + hist[(2 * t)     * NP1 + g];
    if (2 * t + 1 < B) cur[2 * t + 1] = ex + a0 + hist[(2 * t + 1) * NP1 + g];
    __syncthreads();
    int e0 = g * chunk;
    int e1 = min(E, e0 + chunk);
    for (int e = e0 + t; e < e1; e += 256) {
        int d = dst[e];
        int p = atomicAdd(&cur[d >> BSH], 1);   // LDS atomic
        bucketed[p] = (unsigned)src[e] | ((unsigned)(d & 255) << 17);
    }
}

// ---- phase 4: per-bucket CSR finalize (256 nodes/bucket) ----------------
__global__ __launch_bounds__(256) void k_csr(const unsigned* __restrict__ bucketed,
                                             const int* __restrict__ btotal,
                                             int* __restrict__ csr_src,
                                             int* __restrict__ rowptr,   // N+1
                                             float* __restrict__ dinv_g,
                                             int E, int B, int N) {
    const int b = blockIdx.x;
    const int t = threadIdx.x;
    __shared__ int sb[MAXB];
    __shared__ int s[256];
    __shared__ int sdeg[256], sscan[256], cur[256];
    // exclusive scan of btotal -> sb (bucket bases)
    int a0 = (2 * t     < B) ? btotal[2 * t]     : 0;
    int a1 = (2 * t + 1 < B) ? btotal[2 * t + 1] : 0;
    int pair = a0 + a1;
    s[t] = pair;
    sdeg[t] = 0;
    __syncthreads();
    for (int off = 1; off < 256; off <<= 1) {
        int add = (t >= off) ? s[t - off] : 0;
        __syncthreads();
        s[t] += add;
        __syncthreads();
    }
    int ex = s[t] - pair;
    if (2 * t     < B) sb[2 * t]     = ex;
    if (2 * t + 1 < B) sb[2 * t + 1] = ex + a0;
    __syncthreads();

    const int base = sb[b];
    const int cnt = btotal[b];
    const int node0 = b << BSH;

    for (int i = t; i < cnt; i += 256)
        atomicAdd(&sdeg[bucketed[base + i] >> 17], 1);
    __syncthreads();
    sscan[t] = sdeg[t];
    __syncthreads();
    for (int off = 1; off < 256; off <<= 1) {
        int add = (t >= off) ? sscan[t - off] : 0;
        __syncthreads();
        sscan[t] += add;
        __syncthreads();
    }
    {
        int rs = sscan[t] - sdeg[t];   // exclusive
        cur[t] = rs;
        int node = node0 + t;
        if (node < N) {
            rowptr[node] = base + rs;
            dinv_g[node] = rsqrtf((float)(sdeg[t] + 1));   // +1 self-loop
        }
    }
    if (b == B - 1 && t == 0) rowptr[N] = E;
    __syncthreads();
    for (int i = t; i < cnt; i += 256) {
        unsigned w = bucketed[base + i];
        int p = atomicAdd(&cur[w >> 17], 1);   // LDS atomic
        csr_src[base + p] = (int)(w & 0x1FFFFu);
    }
}

// ---- MFMA gemm: xs = bf16(dinv * (x @ W)), packed bf16x2 ----------------
// Wt staged into LDS once per block, XOR-swizzled (chunk c16 at c16^(row&7)).
// 2 row-tiles per wave; B-fragments via ds_read_b128 (uniform 8/bank = free).
// Grid (N+128)>>7 covers dummy row N: the grow2==N lane-group writes zeros.
__global__ __launch_bounds__(256) void k_gemm(const float* __restrict__ x,
                                              const unsigned short* __restrict__ Wt,
                                              const float* __restrict__ dinv,
                                              unsigned* __restrict__ xs_out, int N) {
    __shared__ uint4 wt_lds[128][16];           // 32 KB swizzled Wt
    __shared__ short out_lds[8][16][136];       // [wv*2+tile][row][col] wave-private
    const int t = threadIdx.x;
    const int wv = t >> 6;
    const int lane = t & 63;
    const int quad = lane >> 4;
    const int lid = lane & 15;
    const int row0 = blockIdx.x * 128 + wv * 32;   // this wave's 32 rows

    // stage Wt -> LDS, swizzled (8 x uint4 per thread, one-time)
    {
        const uint4* wg = (const uint4*)Wt;     // 2048 chunks of 16 B
#pragma unroll
        for (int i = 0; i < 8; ++i) {
            int g16 = t * 8 + i;
            int r = g16 >> 4, c16 = g16 & 15;
            wt_lds[r][c16 ^ (r & 7)] = wg[g16];
        }
    }

    // load + convert x tiles BEFORE the barrier (HBM latency hides under staging)
    short8 af0[4], af1[4];
    {
        int r0 = row0 + lid;       int r0c = r0 < N ? r0 : N - 1;
        int r1 = row0 + 16 + lid;  int r1c = r1 < N ? r1 : N - 1;
#pragma unroll
        for (int q = 0; q < 4; ++q) {
            const float4* xr0 = (const float4*)(x + (size_t)r0c * 128 + q * 32 + quad * 8);
            const float4* xr1 = (const float4*)(x + (size_t)r1c * 128 + q * 32 + quad * 8);
            float4 f0 = xr0[0], f1 = xr0[1];
            float4 g0 = xr1[0], g1 = xr1[1];
            af0[q][0] = (short)f2b(f0.x); af0[q][1] = (short)f2b(f0.y);
            af0[q][2] = (short)f2b(f0.z); af0[q][3] = (short)f2b(f0.w);
            af0[q][4] = (short)f2b(f1.x); af0[q][5] = (short)f2b(f1.y);
            af0[q][6] = (short)f2b(f1.z); af0[q][7] = (short)f2b(f1.w);
            af1[q][0] = (short)f2b(g0.x); af1[q][1] = (short)f2b(g0.y);
            af1[q][2] = (short)f2b(g0.z); af1[q][3] = (short)f2b(g0.w);
            af1[q][4] = (short)f2b(g1.x); af1[q][5] = (short)f2b(g1.y);
            af1[q][6] = (short)f2b(g1.z); af1[q][7] = (short)f2b(g1.w);
        }
    }

    float4 dv0, dv1;
    {
        int dr0 = row0 + quad * 4;
        int dr1 = row0 + 16 + quad * 4;
        if (dr0 + 3 < N) dv0 = *(const float4*)(dinv + dr0);
        else {
            dv0.x = dinv[min(dr0 + 0, N - 1)];
            dv0.y = dinv[min(dr0 + 1, N - 1)];
            dv0.z = dinv[min(dr0 + 2, N - 1)];
            dv0.w = dinv[min(dr0 + 3, N - 1)];
        }
        if (dr1 + 3 < N) dv1 = *(const float4*)(dinv + dr1);
        else {
            dv1.x = dinv[min(dr1 + 0, N - 1)];
            dv1.y = dinv[min(dr1 + 1, N - 1)];
            dv1.z = dinv[min(dr1 + 2, N - 1)];
            dv1.w = dinv[min(dr1 + 3, N - 1)];
        }
    }

    __syncthreads();                            // wt_lds ready

#pragma unroll
    for (int c = 0; c < 8; ++c) {
        f32x4 a0 = {0.f, 0.f, 0.f, 0.f};
        f32x4 a1 = {0.f, 0.f, 0.f, 0.f};
        const int r = c * 16 + lid;             // Wt row this lane needs
        const int rx = r & 7;
#pragma unroll
        for (int q = 0; q < 4; ++q) {
            short8 bq = *(const short8*)&wt_lds[r][(q * 4 + quad) ^ rx];
            a0 = __builtin_amdgcn_mfma_f32_16x16x32_bf16(af0[q], bq, a0, 0, 0, 0);
            a1 = __builtin_amdgcn_mfma_f32_16x16x32_bf16(af1[q], bq, a1, 0, 0, 0);
        }
        const int sb = wv * 2;
        out_lds[sb + 0][quad * 4 + 0][c * 16 + lid] = (short)f2b(a0[0] * dv0.x);
        out_lds[sb + 0][quad * 4 + 1][c * 16 + lid] = (short)f2b(a0[1] * dv0.y);
        out_lds[sb + 0][quad * 4 + 2][c * 16 + lid] = (short)f2b(a0[2] * dv0.z);
        out_lds[sb + 0][quad * 4 + 3][c * 16 + lid] = (short)f2b(a0[3] * dv0.w);
        out_lds[sb + 1][quad * 4 + 0][c * 16 + lid] = (short)f2b(a1[0] * dv1.x);
        out_lds[sb + 1][quad * 4 + 1][c * 16 + lid] = (short)f2b(a1[1] * dv1.y);
        out_lds[sb + 1][quad * 4 + 2][c * 16 + lid] = (short)f2b(a1[2] * dv1.z);
        out_lds[sb + 1][quad * 4 + 3][c * 16 + lid] = (short)f2b(a1[3] * dv1.w);
    }
    // no second barrier: out_lds[wv*2+tl] is written and read only by wave wv

    const int rl = lane >> 2;
    const int cseg = lane & 3;
#pragma unroll
    for (int tl = 0; tl < 2; ++tl) {
        int grow2 = row0 + tl * 16 + rl;
        if (grow2 <= N) {
            uint4* dstp = (uint4*)(xs_out + (size_t)grow2 * 64);
            if (grow2 < N) {
                const uint4* srcp = (const uint4*)((const char*)&out_lds[wv * 2 + tl][rl][0] + cseg * 64);
#pragma unroll
                for (int tt = 0; tt < 4; ++tt) dstp[cseg * 4 + tt] = srcp[tt];
            } else {                              // dummy zero row at index N
                uint4 z = make_uint4(0u, 0u, 0u, 0u);
#pragma unroll
                for (int tt = 0; tt < 4; ++tt) dstp[cseg * 4 + tt] = z;
            }
        }
    }
}

// ---- aggregate: 4 nodes/wave, 16 lanes/node, 8 feats/lane ----------------
// 8 gathers in flight per round; next round's csr indices prefetched during
// gathers; tail slots gather the zeroed row N (hot line). NT out stores.
__global__ __launch_bounds__(256) void k_aggregate(const uint4* __restrict__ xs4,
                                                   const int* __restrict__ csr_src,
                                                   const int* __restrict__ rowptr,
                                                   const float* __restrict__ dinv,
                                                   const float* __restrict__ bias,
                                                   float* __restrict__ out, int N) {
    const int t = threadIdx.x;
    const int lane = t & 63;
    const int sub = lane & 15;           // feature quarter: 8 floats (one uint4)
    const int gbase = lane & 48;         // 16-lane group base within wave
    const int n = blockIdx.x * 16 + (t >> 4);
    if (n >= N) return;

    const int rs = rowptr[n];
    const int re = rowptr[n + 1];
    const float dv = dinv[n];
    const char* xb = (const char*)xs4;
    const unsigned subo = (unsigned)sub << 4;

    float4 a0 = make_float4(0.f, 0.f, 0.f, 0.f);
    float4 a1 = make_float4(0.f, 0.f, 0.f, 0.f);

    int idx = N;                                  // dummy zero row for tail slots
    if (rs + sub < re) idx = csr_src[rs + sub];

    for (int i0 = rs; i0 < re; i0 += 16) {
        const int idx_cur = idx;
        const int i1 = i0 + 16;
        idx = N;                                  // prefetch next round's index
        if (i1 + sub < re) idx = csr_src[i1 + sub];
        int m = re - i0; if (m > 16) m = 16;

        {   // slots 0..7: 8 gathers in flight
            int r0 = __shfl(idx_cur, gbase + 0);
            int r1 = __shfl(idx_cur, gbase + 1);
            int r2 = __shfl(idx_cur, gbase + 2);
            int r3 = __shfl(idx_cur, gbase + 3);
            int r4 = __shfl(idx_cur, gbase + 4);
            int r5 = __shfl(idx_cur, gbase + 5);
            int r6 = __shfl(idx_cur, gbase + 6);
            int r7 = __shfl(idx_cur, gbase + 7);
            uint4 u0 = *(const uint4*)(xb + ((((unsigned)r0) << 8) | subo));
            uint4 u1 = *(const uint4*)(xb + ((((unsigned)r1) << 8) | subo));
            uint4 u2 = *(const uint4*)(xb + ((((unsigned)r2) << 8) | subo));
            uint4 u3 = *(const uint4*)(xb + ((((unsigned)r3) << 8) | subo));
            uint4 u4 = *(const uint4*)(xb + ((((unsigned)r4) << 8) | subo));
            uint4 u5 = *(const uint4*)(xb + ((((unsigned)r5) << 8) | subo));
            uint4 u6 = *(const uint4*)(xb + ((((unsigned)r6) << 8) | subo));
            uint4 u7 = *(const uint4*)(xb + ((((unsigned)r7) << 8) | subo));
            acc4(a0, u0.x, u0.y); acc4(a1, u0.z, u0.w);
            acc4(a0, u1.x, u1.y); acc4(a1, u1.z, u1.w);
            acc4(a0, u2.x, u2.y); acc4(a1, u2.z, u2.w);
            acc4(a0, u3.x, u3.y); acc4(a1, u3.z, u3.w);
            acc4(a0, u4.x, u4.y); acc4(a1, u4.z, u4.w);
            acc4(a0, u5.x, u5.y); acc4(a1, u5.z, u5.w);
            acc4(a0, u6.x, u6.y); acc4(a1, u6.z, u6.w);
            acc4(a0, u7.x, u7.y); acc4(a1, u7.z, u7.w);
        }
        if (m > 8) {   // slots 8..15
            int r0 = __shfl(idx_cur, gbase + 8);
            int r1 = __shfl(idx_cur, gbase + 9);
            int r2 = __shfl(idx_cur, gbase + 10);
            int r3 = __shfl(idx_cur, gbase + 11);
            int r4 = __shfl(idx_cur, gbase + 12);
            int r5 = __shfl(idx_cur, gbase + 13);
            int r6 = __shfl(idx_cur, gbase + 14);
            int r7 = __shfl(idx_cur, gbase + 15);
            uint4 u0 = *(const uint4*)(xb + ((((unsigned)r0) << 8) | subo));
            uint4 u1 = *(const uint4*)(xb + ((((unsigned)r1) << 8) | subo));
            uint4 u2 = *(const uint4*)(xb + ((((unsigned)r2) << 8) | subo));
            uint4 u3 = *(const uint4*)(xb + ((((unsigned)r3) << 8) | subo));
            uint4 u4 = *(const uint4*)(xb + ((((unsigned)r4) << 8) | subo));
            uint4 u5 = *(const uint4*)(xb + ((((unsigned)r5) << 8) | subo));
            uint4 u6 = *(const uint4*)(xb + ((((unsigned)r6) << 8) | subo));
            uint4 u7 = *(const uint4*)(xb + ((((unsigned)r7) << 8) | subo));
            acc4(a0, u0.x, u0.y); acc4(a1, u0.z, u0.w);
            acc4(a0, u1.x, u1.y); acc4(a1, u1.z, u1.w);
            acc4(a0, u2.x, u2.y); acc4(a1, u2.z, u2.w);
            acc4(a0, u3.x, u3.y); acc4(a1, u3.z, u3.w);
            acc4(a0, u4.x, u4.y); acc4(a1, u4.z, u4.w);
            acc4(a0, u5.x, u5.y); acc4(a1, u5.z, u5.w);
            acc4(a0, u6.x, u6.y); acc4(a1, u6.z, u6.w);
            acc4(a0, u7.x, u7.y); acc4(a1, u7.z, u7.w);
        }
    }

    // self-loop (xs row n already dinv[n]-scaled)
    uint4 su = *(const uint4*)(xb + ((((unsigned)n) << 8) | subo));
    acc4(a0, su.x, su.y);
    acc4(a1, su.z, su.w);

    const float4* bp = (const float4*)bias;
    float4 b0 = bp[sub * 2];
    float4 b1 = bp[sub * 2 + 1];
    f32x4 o0, o1;
    o0[0] = fmaxf(dv * a0.x + b0.x, 0.f);
    o0[1] = fmaxf(dv * a0.y + b0.y, 0.f);
    o0[2] = fmaxf(dv * a0.z + b0.z, 0.f);
    o0[3] = fmaxf(dv * a0.w + b0.w, 0.f);
    o1[0] = fmaxf(dv * a1.x + b1.x, 0.f);
    o1[1] = fmaxf(dv * a1.y + b1.y, 0.f);
    o1[2] = fmaxf(dv * a1.z + b1.z, 0.f);
    o1[3] = fmaxf(dv * a1.w + b1.w, 0.f);

    f32x4* op = (f32x4*)(out + (size_t)n * 128 + sub * 8);
    __builtin_nontemporal_store(o0, op);          // out is write-once: don't
    __builtin_nontemporal_store(o1, op + 1);      // evict xs gather lines
}

extern "C" void kernel_launch(void* const* d_in, const int* in_sizes, int n_in,
                              void* d_out, int out_size, void* d_ws, size_t ws_size,
                              hipStream_t stream) {
    const float* x   = (const float*)d_in[0];
    const int*   ei  = (const int*)d_in[1];     // [2, E] flat: src then dst
    const float* W   = (const float*)d_in[2];
    const float* b   = (const float*)d_in[3];
    float*       out = (float*)d_out;

    const int N = in_sizes[0] / 128;
    const int E = in_sizes[1] / 2;
    const int* src = ei;
    const int* dst = ei + E;

    const int B = (N + 255) >> BSH;          // 392 buckets (<= MAXB)
    const int M = B * NP1;                   // hist entries
    const int chunk = (E + NP1 - 1) / NP1;   // edges per phase-1 block

    // workspace carve (256B aligned)
    auto align = [](size_t v) { return (v + 255) & ~(size_t)255; };
    char* p = (char*)d_ws;
    int*            hist     = (int*)p;            p += align((size_t)M * 4);
    int*            btotal   = (int*)p;            p += align((size_t)B * 4);
    int*            rowptr   = (int*)p;            p += align(((size_t)N + 1) * 4);
    float*          dinv     = (float*)p;          p += align((size_t)N * 4);
    unsigned*       bucketed = (unsigned*)p;       p += align((size_t)E * 4);
    int*            csr_src  = (int*)p;            p += align((size_t)E * 4);
    unsigned*       xs       = (unsigned*)p;       p += align(((size_t)N + 1) * 64 * 4);
    unsigned short* Wt       = (unsigned short*)p; p += align(128 * 128 * 2);
    (void)ws_size;

    k_hist    <<<NP1, 256, 0, stream>>>(dst, hist, W, Wt, E, B, chunk);
    k_scanrow <<<B, 256, 0, stream>>>(hist, btotal, B);
    k_scatter <<<NP1, 256, 0, stream>>>(src, dst, hist, btotal, bucketed, E, B, chunk);
    k_csr     <<<B, 256, 0, stream>>>(bucketed, btotal, csr_src, rowptr,
                                      dinv, E, B, N);
    k_gemm    <<<(N + 128) >> 7, 256, 0, stream>>>(x, Wt, dinv, xs, N);  // covers row N
    k_aggregate<<<(N + 15) / 16, 256, 0, stream>>>((const uint4*)xs, csr_src, rowptr,
                                                   dinv, b, out, N);
}

// Round 12
// 216.579 us; speedup vs baseline: 1.1944x; 1.0401x over previous
//
#include <hip/hip_runtime.h>
#include <hip/hip_bf16.h>

// GCNConv: out = relu( D^{-1/2} (A + I) D^{-1/2} (x @ W) + b )
// CSR build via atomic-free two-phase bucket sort (bucket = dst>>8, 256 nodes):
//   1. k_hist   : per-block LDS histograms -> hist[block][bucket] CONTIGUOUS
//                 writes (round 12: was hist[bucket][block], 4B x 2KB-stride
//                 scatter = ~16x write amplification) (+ Wt convert)
//   2. k_scanrow: per-bucket exclusive scan; reads column strided (L2-cheap),
//                 writes scan_out[bucket][block] CONTIGUOUS (+ btotal)
//   3. k_scatter: edges -> bucket-grouped packed array (src | dlow<<17);
//                 cursor init reads scan_out strided (L2-cheap)
//   4. k_csr    : per-bucket LDS hist+scan+rank -> csr_src, rowptr[N+1], dinv
//   5. k_gemm   : xs = bf16( dinv[n] * (x[n] @ W) ), MFMA 16x16x32, Wt staged
//                 in LDS XOR-swizzled (round 11: killed L2 B-operand path,
//                 44us -> under the 41us fills). out_lds wave-private.
//   6. k_aggregate: 4 nodes/wave, 8 gathers in flight, csr prefetch, NT stores.
//                 PATTERN CEILING (~62us, 4TB/s L2-miss stream) — measured
//                 invariant across 5 different schedules (rounds 2,3,6,8,11).
// Harness rules: NO cooperative launch, NO inter-block spin (graph capture).
// Harness poisons the 256MiB workspace every iteration (41us fill) — floor;
// fills cap the top-5 view at 41us, so sub-41us kernels are invisible.

#define NP1 512          // blocks in phase-1 (hist/scatter): 2 per CU
#define BSH 8            // bucket shift: 256 nodes per bucket
#define MAXB 512         // bucket count cap (N <= 131072)

typedef short  short8 __attribute__((ext_vector_type(8)));
typedef float  f32x4  __attribute__((ext_vector_type(4)));

__device__ inline unsigned short f2b(float f) {   // fp32 -> bf16 RNE
    unsigned u = __float_as_uint(f);
    return (unsigned short)((u + 0x7fffu + ((u >> 16) & 1u)) >> 16);
}

__device__ inline void acc4(float4& a, unsigned lo, unsigned hi) {
    a.x += __uint_as_float(lo << 16);
    a.y += __uint_as_float(lo & 0xffff0000u);
    a.z += __uint_as_float(hi << 16);
    a.w += __uint_as_float(hi & 0xffff0000u);
}

// ---- phase 1: bucket histogram (+ fused Wt = bf16(W^T)) -----------------
// hist layout: [block g][bucket b] — contiguous per-block writes.
__global__ __launch_bounds__(256) void k_hist(const int* __restrict__ dst,
                                              int* __restrict__ hist,
                                              const float* __restrict__ W,
                                              unsigned short* __restrict__ Wt,
                                              int E, int B, int chunk) {
    __shared__ int h[MAXB];
    for (int i = threadIdx.x; i < B; i += 256) h[i] = 0;
    __syncthreads();
    int e0 = blockIdx.x * chunk;
    int e1 = min(E, e0 + chunk);
    for (int e = e0 + threadIdx.x; e < e1; e += 256)
        atomicAdd(&h[dst[e] >> BSH], 1);
    __syncthreads();
    for (int i = threadIdx.x; i < B; i += 256)
        hist[blockIdx.x * B + i] = h[i];          // contiguous store
    if (blockIdx.x < 64) {                      // fused weight transpose
        int i = blockIdx.x * 256 + threadIdx.x; // 0..16383
        int k = i >> 7, n = i & 127;
        Wt[n * 128 + k] = f2b(W[k * 128 + n]);
    }
}

// ---- phase 2: per-bucket exclusive scan over the NP1 block columns ------
// Reads hist[g][b] strided (L2-resident, cheap); writes scan_out[b][g]
// contiguous + btotal[b].
__global__ __launch_bounds__(256) void k_scanrow(const int* __restrict__ hist,
                                                 int* __restrict__ scan_out,
                                                 int* __restrict__ btotal, int B) {
    __shared__ int s[256];
    const int b = blockIdx.x;
    const int t = threadIdx.x;
    int v0 = hist[(2 * t)     * B + b];           // strided read
    int v1 = hist[(2 * t + 1) * B + b];
    int pair = v0 + v1;
    s[t] = pair;
    __syncthreads();
    for (int off = 1; off < 256; off <<= 1) {
        int add = (t >= off) ? s[t - off] : 0;
        __syncthreads();
        s[t] += add;
        __syncthreads();
    }
    int exc = s[t] - pair;                      // exclusive prefix of this pair
    scan_out[b * NP1 + 2 * t]     = exc;          // contiguous store
    scan_out[b * NP1 + 2 * t + 1] = exc + v0;
    if (t == 255) btotal[b] = s[255];
}

// ---- phase 3: bucket-grouped scatter (LDS cursors; in-block btotal scan) ----
__global__ __launch_bounds__(256) void k_scatter(const int* __restrict__ src,
                                                 const int* __restrict__ dst,
                                                 const int* __restrict__ scan_out,
                                                 const int* __restrict__ btotal,
                                                 unsigned* __restrict__ bucketed,
                                                 int E, int B, int chunk) {
    __shared__ int cur[MAXB];
    __shared__ int s[256];
    const int t = threadIdx.x;
    const int g = blockIdx.x;
    // exclusive scan of btotal (pairs), fused with cursor init
    int a0 = (2 * t     < B) ? btotal[2 * t]     : 0;
    int a1 = (2 * t + 1 < B) ? btotal[2 * t + 1] : 0;
    int pair = a0 + a1;
    s[t] = pair;
    __syncthreads();
    for (int off = 1; off < 256; off <<= 1) {
        int add = (t >= off) ? s[t - off] : 0;
        __syncthreads();
        s[t] += add;
        __syncthreads();
    }
    int ex = s[t] - pair;
    if (2 * t     < B) cur[2 * t]     = ex      + scan_out[(2 * t)     * NP1 + g];
    if (2 * t + 1 < B) cur[2 * t + 1] = ex + a0 + scan_out[(2 * t + 1) * NP1 + g];
    __syncthreads();
    int e0 = g * chunk;
    int e1 = min(E, e0 + chunk);
    for (int e = e0 + t; e < e1; e += 256) {
        int d = dst[e];
        int p = atomicAdd(&cur[d >> BSH], 1);   // LDS atomic
        bucketed[p] = (unsigned)src[e] | ((unsigned)(d & 255) << 17);
    }
}

// ---- phase 4: per-bucket CSR finalize (256 nodes/bucket) ----------------
__global__ __launch_bounds__(256) void k_csr(const unsigned* __restrict__ bucketed,
                                             const int* __restrict__ btotal,
                                             int* __restrict__ csr_src,
                                             int* __restrict__ rowptr,   // N+1
                                             float* __restrict__ dinv_g,
                                             int E, int B, int N) {
    const int b = blockIdx.x;
    const int t = threadIdx.x;
    __shared__ int sb[MAXB];
    __shared__ int s[256];
    __shared__ int sdeg[256], sscan[256], cur[256];
    // exclusive scan of btotal -> sb (bucket bases)
    int a0 = (2 * t     < B) ? btotal[2 * t]     : 0;
    int a1 = (2 * t + 1 < B) ? btotal[2 * t + 1] : 0;
    int pair = a0 + a1;
    s[t] = pair;
    sdeg[t] = 0;
    __syncthreads();
    for (int off = 1; off < 256; off <<= 1) {
        int add = (t >= off) ? s[t - off] : 0;
        __syncthreads();
        s[t] += add;
        __syncthreads();
    }
    int ex = s[t] - pair;
    if (2 * t     < B) sb[2 * t]     = ex;
    if (2 * t + 1 < B) sb[2 * t + 1] = ex + a0;
    __syncthreads();

    const int base = sb[b];
    const int cnt = btotal[b];
    const int node0 = b << BSH;

    for (int i = t; i < cnt; i += 256)
        atomicAdd(&sdeg[bucketed[base + i] >> 17], 1);
    __syncthreads();
    sscan[t] = sdeg[t];
    __syncthreads();
    for (int off = 1; off < 256; off <<= 1) {
        int add = (t >= off) ? sscan[t - off] : 0;
        __syncthreads();
        sscan[t] += add;
        __syncthreads();
    }
    {
        int rs = sscan[t] - sdeg[t];   // exclusive
        cur[t] = rs;
        int node = node0 + t;
        if (node < N) {
            rowptr[node] = base + rs;
            dinv_g[node] = rsqrtf((float)(sdeg[t] + 1));   // +1 self-loop
        }
    }
    if (b == B - 1 && t == 0) rowptr[N] = E;
    __syncthreads();
    for (int i = t; i < cnt; i += 256) {
        unsigned w = bucketed[base + i];
        int p = atomicAdd(&cur[w >> 17], 1);   // LDS atomic
        csr_src[base + p] = (int)(w & 0x1FFFFu);
    }
}

// ---- MFMA gemm: xs = bf16(dinv * (x @ W)), packed bf16x2 ----------------
// Wt staged into LDS once per block, XOR-swizzled (chunk c16 at c16^(row&7)).
// 2 row-tiles per wave; B-fragments via ds_read_b128 (uniform 8/bank = free).
// Grid (N+128)>>7 covers dummy row N: the grow2==N lane-group writes zeros.
__global__ __launch_bounds__(256) void k_gemm(const float* __restrict__ x,
                                              const unsigned short* __restrict__ Wt,
                                              const float* __restrict__ dinv,
                                              unsigned* __restrict__ xs_out, int N) {
    __shared__ uint4 wt_lds[128][16];           // 32 KB swizzled Wt
    __shared__ short out_lds[8][16][136];       // [wv*2+tile][row][col] wave-private
    const int t = threadIdx.x;
    const int wv = t >> 6;
    const int lane = t & 63;
    const int quad = lane >> 4;
    const int lid = lane & 15;
    const int row0 = blockIdx.x * 128 + wv * 32;   // this wave's 32 rows

    // stage Wt -> LDS, swizzled (8 x uint4 per thread, one-time)
    {
        const uint4* wg = (const uint4*)Wt;     // 2048 chunks of 16 B
#pragma unroll
        for (int i = 0; i < 8; ++i) {
            int g16 = t * 8 + i;
            int r = g16 >> 4, c16 = g16 & 15;
            wt_lds[r][c16 ^ (r & 7)] = wg[g16];
        }
    }

    // load + convert x tiles BEFORE the barrier (HBM latency hides under staging)
    short8 af0[4], af1[4];
    {
        int r0 = row0 + lid;       int r0c = r0 < N ? r0 : N - 1;
        int r1 = row0 + 16 + lid;  int r1c = r1 < N ? r1 : N - 1;
#pragma unroll
        for (int q = 0; q < 4; ++q) {
            const float4* xr0 = (const float4*)(x + (size_t)r0c * 128 + q * 32 + quad * 8);
            const float4* xr1 = (const float4*)(x + (size_t)r1c * 128 + q * 32 + quad * 8);
            float4 f0 = xr0[0], f1 = xr0[1];
            float4 g0 = xr1[0], g1 = xr1[1];
            af0[q][0] = (short)f2b(f0.x); af0[q][1] = (short)f2b(f0.y);
            af0[q][2] = (short)f2b(f0.z); af0[q][3] = (short)f2b(f0.w);
            af0[q][4] = (short)f2b(f1.x); af0[q][5] = (short)f2b(f1.y);
            af0[q][6] = (short)f2b(f1.z); af0[q][7] = (short)f2b(f1.w);
            af1[q][0] = (short)f2b(g0.x); af1[q][1] = (short)f2b(g0.y);
            af1[q][2] = (short)f2b(g0.z); af1[q][3] = (short)f2b(g0.w);
            af1[q][4] = (short)f2b(g1.x); af1[q][5] = (short)f2b(g1.y);
            af1[q][6] = (short)f2b(g1.z); af1[q][7] = (short)f2b(g1.w);
        }
    }

    float4 dv0, dv1;
    {
        int dr0 = row0 + quad * 4;
        int dr1 = row0 + 16 + quad * 4;
        if (dr0 + 3 < N) dv0 = *(const float4*)(dinv + dr0);
        else {
            dv0.x = dinv[min(dr0 + 0, N - 1)];
            dv0.y = dinv[min(dr0 + 1, N - 1)];
            dv0.z = dinv[min(dr0 + 2, N - 1)];
            dv0.w = dinv[min(dr0 + 3, N - 1)];
        }
        if (dr1 + 3 < N) dv1 = *(const float4*)(dinv + dr1);
        else {
            dv1.x = dinv[min(dr1 + 0, N - 1)];
            dv1.y = dinv[min(dr1 + 1, N - 1)];
            dv1.z = dinv[min(dr1 + 2, N - 1)];
            dv1.w = dinv[min(dr1 + 3, N - 1)];
        }
    }

    __syncthreads();                            // wt_lds ready

#pragma unroll
    for (int c = 0; c < 8; ++c) {
        f32x4 a0 = {0.f, 0.f, 0.f, 0.f};
        f32x4 a1 = {0.f, 0.f, 0.f, 0.f};
        const int r = c * 16 + lid;             // Wt row this lane needs
        const int rx = r & 7;
#pragma unroll
        for (int q = 0; q < 4; ++q) {
            short8 bq = *(const short8*)&wt_lds[r][(q * 4 + quad) ^ rx];
            a0 = __builtin_amdgcn_mfma_f32_16x16x32_bf16(af0[q], bq, a0, 0, 0, 0);
            a1 = __builtin_amdgcn_mfma_f32_16x16x32_bf16(af1[q], bq, a1, 0, 0, 0);
        }
        const int sb = wv * 2;
        out_lds[sb + 0][quad * 4 + 0][c * 16 + lid] = (short)f2b(a0[0] * dv0.x);
        out_lds[sb + 0][quad * 4 + 1][c * 16 + lid] = (short)f2b(a0[1] * dv0.y);
        out_lds[sb + 0][quad * 4 + 2][c * 16 + lid] = (short)f2b(a0[2] * dv0.z);
        out_lds[sb + 0][quad * 4 + 3][c * 16 + lid] = (short)f2b(a0[3] * dv0.w);
        out_lds[sb + 1][quad * 4 + 0][c * 16 + lid] = (short)f2b(a1[0] * dv1.x);
        out_lds[sb + 1][quad * 4 + 1][c * 16 + lid] = (short)f2b(a1[1] * dv1.y);
        out_lds[sb + 1][quad * 4 + 2][c * 16 + lid] = (short)f2b(a1[2] * dv1.z);
        out_lds[sb + 1][quad * 4 + 3][c * 16 + lid] = (short)f2b(a1[3] * dv1.w);
    }
    // no second barrier: out_lds[wv*2+tl] is written and read only by wave wv

    const int rl = lane >> 2;
    const int cseg = lane & 3;
#pragma unroll
    for (int tl = 0; tl < 2; ++tl) {
        int grow2 = row0 + tl * 16 + rl;
        if (grow2 <= N) {
            uint4* dstp = (uint4*)(xs_out + (size_t)grow2 * 64);
            if (grow2 < N) {
                const uint4* srcp = (const uint4*)((const char*)&out_lds[wv * 2 + tl][rl][0] + cseg * 64);
#pragma unroll
                for (int tt = 0; tt < 4; ++tt) dstp[cseg * 4 + tt] = srcp[tt];
            } else {                              // dummy zero row at index N
                uint4 z = make_uint4(0u, 0u, 0u, 0u);
#pragma unroll
                for (int tt = 0; tt < 4; ++tt) dstp[cseg * 4 + tt] = z;
            }
        }
    }
}

// ---- aggregate: 4 nodes/wave, 16 lanes/node, 8 feats/lane ----------------
// 8 gathers in flight per round; next round's csr indices prefetched during
// gathers; tail slots gather the zeroed row N (hot line). NT out stores.
__global__ __launch_bounds__(256) void k_aggregate(const uint4* __restrict__ xs4,
                                                   const int* __restrict__ csr_src,
                                                   const int* __restrict__ rowptr,
                                                   const float* __restrict__ dinv,
                                                   const float* __restrict__ bias,
                                                   float* __restrict__ out, int N) {
    const int t = threadIdx.x;
    const int lane = t & 63;
    const int sub = lane & 15;           // feature quarter: 8 floats (one uint4)
    const int gbase = lane & 48;         // 16-lane group base within wave
    const int n = blockIdx.x * 16 + (t >> 4);
    if (n >= N) return;

    const int rs = rowptr[n];
    const int re = rowptr[n + 1];
    const float dv = dinv[n];
    const char* xb = (const char*)xs4;
    const unsigned subo = (unsigned)sub << 4;

    float4 a0 = make_float4(0.f, 0.f, 0.f, 0.f);
    float4 a1 = make_float4(0.f, 0.f, 0.f, 0.f);

    int idx = N;                                  // dummy zero row for tail slots
    if (rs + sub < re) idx = csr_src[rs + sub];

    for (int i0 = rs; i0 < re; i0 += 16) {
        const int idx_cur = idx;
        const int i1 = i0 + 16;
        idx = N;                                  // prefetch next round's index
        if (i1 + sub < re) idx = csr_src[i1 + sub];
        int m = re - i0; if (m > 16) m = 16;

        {   // slots 0..7: 8 gathers in flight
            int r0 = __shfl(idx_cur, gbase + 0);
            int r1 = __shfl(idx_cur, gbase + 1);
            int r2 = __shfl(idx_cur, gbase + 2);
            int r3 = __shfl(idx_cur, gbase + 3);
            int r4 = __shfl(idx_cur, gbase + 4);
            int r5 = __shfl(idx_cur, gbase + 5);
            int r6 = __shfl(idx_cur, gbase + 6);
            int r7 = __shfl(idx_cur, gbase + 7);
            uint4 u0 = *(const uint4*)(xb + ((((unsigned)r0) << 8) | subo));
            uint4 u1 = *(const uint4*)(xb + ((((unsigned)r1) << 8) | subo));
            uint4 u2 = *(const uint4*)(xb + ((((unsigned)r2) << 8) | subo));
            uint4 u3 = *(const uint4*)(xb + ((((unsigned)r3) << 8) | subo));
            uint4 u4 = *(const uint4*)(xb + ((((unsigned)r4) << 8) | subo));
            uint4 u5 = *(const uint4*)(xb + ((((unsigned)r5) << 8) | subo));
            uint4 u6 = *(const uint4*)(xb + ((((unsigned)r6) << 8) | subo));
            uint4 u7 = *(const uint4*)(xb + ((((unsigned)r7) << 8) | subo));
            acc4(a0, u0.x, u0.y); acc4(a1, u0.z, u0.w);
            acc4(a0, u1.x, u1.y); acc4(a1, u1.z, u1.w);
            acc4(a0, u2.x, u2.y); acc4(a1, u2.z, u2.w);
            acc4(a0, u3.x, u3.y); acc4(a1, u3.z, u3.w);
            acc4(a0, u4.x, u4.y); acc4(a1, u4.z, u4.w);
            acc4(a0, u5.x, u5.y); acc4(a1, u5.z, u5.w);
            acc4(a0, u6.x, u6.y); acc4(a1, u6.z, u6.w);
            acc4(a0, u7.x, u7.y); acc4(a1, u7.z, u7.w);
        }
        if (m > 8) {   // slots 8..15
            int r0 = __shfl(idx_cur, gbase + 8);
            int r1 = __shfl(idx_cur, gbase + 9);
            int r2 = __shfl(idx_cur, gbase + 10);
            int r3 = __shfl(idx_cur, gbase + 11);
            int r4 = __shfl(idx_cur, gbase + 12);
            int r5 = __shfl(idx_cur, gbase + 13);
            int r6 = __shfl(idx_cur, gbase + 14);
            int r7 = __shfl(idx_cur, gbase + 15);
            uint4 u0 = *(const uint4*)(xb + ((((unsigned)r0) << 8) | subo));
            uint4 u1 = *(const uint4*)(xb + ((((unsigned)r1) << 8) | subo));
            uint4 u2 = *(const uint4*)(xb + ((((unsigned)r2) << 8) | subo));
            uint4 u3 = *(const uint4*)(xb + ((((unsigned)r3) << 8) | subo));
            uint4 u4 = *(const uint4*)(xb + ((((unsigned)r4) << 8) | subo));
            uint4 u5 = *(const uint4*)(xb + ((((unsigned)r5) << 8) | subo));
            uint4 u6 = *(const uint4*)(xb + ((((unsigned)r6) << 8) | subo));
            uint4 u7 = *(const uint4*)(xb + ((((unsigned)r7) << 8) | subo));
            acc4(a0, u0.x, u0.y); acc4(a1, u0.z, u0.w);
            acc4(a0, u1.x, u1.y); acc4(a1, u1.z, u1.w);
            acc4(a0, u2.x, u2.y); acc4(a1, u2.z, u2.w);
            acc4(a0, u3.x, u3.y); acc4(a1, u3.z, u3.w);
            acc4(a0, u4.x, u4.y); acc4(a1, u4.z, u4.w);
            acc4(a0, u5.x, u5.y); acc4(a1, u5.z, u5.w);
            acc4(a0, u6.x, u6.y); acc4(a1, u6.z, u6.w);
            acc4(a0, u7.x, u7.y); acc4(a1, u7.z, u7.w);
        }
    }

    // self-loop (xs row n already dinv[n]-scaled)
    uint4 su = *(const uint4*)(xb + ((((unsigned)n) << 8) | subo));
    acc4(a0, su.x, su.y);
    acc4(a1, su.z, su.w);

    const float4* bp = (const float4*)bias;
    float4 b0 = bp[sub * 2];
    float4 b1 = bp[sub * 2 + 1];
    f32x4 o0, o1;
    o0[0] = fmaxf(dv * a0.x + b0.x, 0.f);
    o0[1] = fmaxf(dv * a0.y + b0.y, 0.f);
    o0[2] = fmaxf(dv * a0.z + b0.z, 0.f);
    o0[3] = fmaxf(dv * a0.w + b0.w, 0.f);
    o1[0] = fmaxf(dv * a1.x + b1.x, 0.f);
    o1[1] = fmaxf(dv * a1.y + b1.y, 0.f);
    o1[2] = fmaxf(dv * a1.z + b1.z, 0.f);
    o1[3] = fmaxf(dv * a1.w + b1.w, 0.f);

    f32x4* op = (f32x4*)(out + (size_t)n * 128 + sub * 8);
    __builtin_nontemporal_store(o0, op);          // out is write-once: don't
    __builtin_nontemporal_store(o1, op + 1);      // evict xs gather lines
}

extern "C" void kernel_launch(void* const* d_in, const int* in_sizes, int n_in,
                              void* d_out, int out_size, void* d_ws, size_t ws_size,
                              hipStream_t stream) {
    const float* x   = (const float*)d_in[0];
    const int*   ei  = (const int*)d_in[1];     // [2, E] flat: src then dst
    const float* W   = (const float*)d_in[2];
    const float* b   = (const float*)d_in[3];
    float*       out = (float*)d_out;

    const int N = in_sizes[0] / 128;
    const int E = in_sizes[1] / 2;
    const int* src = ei;
    const int* dst = ei + E;

    const int B = (N + 255) >> BSH;          // 392 buckets (<= MAXB)
    const int M = B * NP1;                   // hist entries
    const int chunk = (E + NP1 - 1) / NP1;   // edges per phase-1 block

    // workspace carve (256B aligned)
    auto align = [](size_t v) { return (v + 255) & ~(size_t)255; };
    char* p = (char*)d_ws;
    int*            hist     = (int*)p;            p += align((size_t)M * 4);
    int*            scan_out = (int*)p;            p += align((size_t)M * 4);
    int*            btotal   = (int*)p;            p += align((size_t)B * 4);
    int*            rowptr   = (int*)p;            p += align(((size_t)N + 1) * 4);
    float*          dinv     = (float*)p;          p += align((size_t)N * 4);
    unsigned*       bucketed = (unsigned*)p;       p += align((size_t)E * 4);
    int*            csr_src  = (int*)p;            p += align((size_t)E * 4);
    unsigned*       xs       = (unsigned*)p;       p += align(((size_t)N + 1) * 64 * 4);
    unsigned short* Wt       = (unsigned short*)p; p += align(128 * 128 * 2);
    (void)ws_size;

    k_hist    <<<NP1, 256, 0, stream>>>(dst, hist, W, Wt, E, B, chunk);
    k_scanrow <<<B, 256, 0, stream>>>(hist, scan_out, btotal, B);
    k_scatter <<<NP1, 256, 0, stream>>>(src, dst, scan_out, btotal, bucketed, E, B, chunk);
    k_csr     <<<B, 256, 0, stream>>>(bucketed, btotal, csr_src, rowptr,
                                      dinv, E, B, N);
    k_gemm    <<<(N + 128) >> 7, 256, 0, stream>>>(x, Wt, dinv, xs, N);  // covers row N
    k_aggregate<<<(N + 15) / 16, 256, 0, stream>>>((const uint4*)xs, csr_src, rowptr,
                                                   dinv, b, out, N);
}

// Round 13
// 216.185 us; speedup vs baseline: 1.1966x; 1.0018x over previous
//
#include <hip/hip_runtime.h>
#include <hip/hip_bf16.h>

// GCNConv: out = relu( D^{-1/2} (A + I) D^{-1/2} (x @ W) + b )
// CSR build via atomic-free two-phase bucket sort (bucket = dst>>8, 256 nodes):
//   1. k_hist   : per-block LDS histograms -> hist[block][bucket] contiguous;
//                 ROUND 13: int4 edge reads (4 edges/lane, 4x MLP) + NP1 1024
//                 (4 blocks/CU) (+ Wt convert)
//   2. k_scanrow: per-bucket exclusive scan over 1024 block columns (4/thread),
//                 strided reads (L2-cheap), contiguous writes (+ btotal)
//   3. k_scatter: edges -> bucket-grouped packed array (src | dlow<<17);
//                 ROUND 13: int4 src/dst reads, 4 independent LDS-atomic chains
//   4. k_csr    : per-bucket LDS hist+scan+rank -> csr_src, rowptr[N+1], dinv
//   5. k_gemm   : xs = bf16( dinv[n] * (x[n] @ W) ), MFMA 16x16x32, Wt staged
//                 in LDS XOR-swizzled (round 11). out_lds wave-private.
//   6. k_aggregate: 4 nodes/wave, 8 gathers in flight, csr prefetch, NT stores.
//                 PATTERN CEILING (~62us, 4TB/s L2-miss stream) — invariant
//                 across 6 schedules (rounds 2,3,6,8,11,12). DO NOT TOUCH.
// Structural floor: harness fill (41us, 256MiB poison) + ~dozens of reset
// dispatches per iteration inside the timed window (dispatch-ID spacing ~150).
// Harness rules: NO cooperative launch, NO inter-block spin (graph capture).

#define NP1 1024         // blocks in phase-1 (hist/scatter): 4 per CU
#define BSH 8            // bucket shift: 256 nodes per bucket
#define MAXB 512         // bucket count cap (N <= 131072)

typedef short  short8 __attribute__((ext_vector_type(8)));
typedef float  f32x4  __attribute__((ext_vector_type(4)));

__device__ inline unsigned short f2b(float f) {   // fp32 -> bf16 RNE
    unsigned u = __float_as_uint(f);
    return (unsigned short)((u + 0x7fffu + ((u >> 16) & 1u)) >> 16);
}

__device__ inline void acc4(float4& a, unsigned lo, unsigned hi) {
    a.x += __uint_as_float(lo << 16);
    a.y += __uint_as_float(lo & 0xffff0000u);
    a.z += __uint_as_float(hi << 16);
    a.w += __uint_as_float(hi & 0xffff0000u);
}

// ---- phase 1: bucket histogram (+ fused Wt = bf16(W^T)) -----------------
// hist layout: [block g][bucket b] — contiguous per-block writes.
__global__ __launch_bounds__(256) void k_hist(const int* __restrict__ dst,
                                              int* __restrict__ hist,
                                              const float* __restrict__ W,
                                              unsigned short* __restrict__ Wt,
                                              int E, int B, int chunk) {
    __shared__ int h[MAXB];
    const int t = threadIdx.x;
    for (int i = t; i < B; i += 256) h[i] = 0;
    __syncthreads();
    const int e0 = blockIdx.x * chunk;
    const int e1 = min(E, e0 + chunk);
    const int cnt = e1 - e0;
    if (cnt > 0) {
        if ((E & 3) == 0) {                     // chunk%4==0 -> e0%4==0 -> aligned
            const int nv = cnt >> 2;
            const int4* d4 = (const int4*)(dst + e0);
            for (int i = t; i < nv; i += 256) {
                int4 d = d4[i];                 // 4 edges, independent chains
                atomicAdd(&h[d.x >> BSH], 1);
                atomicAdd(&h[d.y >> BSH], 1);
                atomicAdd(&h[d.z >> BSH], 1);
                atomicAdd(&h[d.w >> BSH], 1);
            }
            for (int e = e0 + (nv << 2) + t; e < e1; e += 256)
                atomicAdd(&h[dst[e] >> BSH], 1);
        } else {                                // alignment fallback
            for (int e = e0 + t; e < e1; e += 256)
                atomicAdd(&h[dst[e] >> BSH], 1);
        }
    }
    __syncthreads();
    for (int i = t; i < B; i += 256)
        hist[blockIdx.x * B + i] = h[i];        // contiguous store
    if (blockIdx.x < 64) {                      // fused weight transpose
        int i = blockIdx.x * 256 + t;           // 0..16383
        int k = i >> 7, n = i & 127;
        Wt[n * 128 + k] = f2b(W[k * 128 + n]);
    }
}

// ---- phase 2: per-bucket exclusive scan over the NP1 block columns ------
// Reads hist[g][b] strided (L2-resident, cheap); 4 columns per thread;
// writes scan_out[b][g] contiguous + btotal[b].
__global__ __launch_bounds__(256) void k_scanrow(const int* __restrict__ hist,
                                                 int* __restrict__ scan_out,
                                                 int* __restrict__ btotal, int B) {
    __shared__ int s[256];
    const int b = blockIdx.x;
    const int t = threadIdx.x;
    int v[4];
    int loc = 0;
#pragma unroll
    for (int k = 0; k < 4; ++k) {
        v[k] = hist[(4 * t + k) * B + b];       // strided read
        loc += v[k];
    }
    s[t] = loc;
    __syncthreads();
    for (int off = 1; off < 256; off <<= 1) {
        int add = (t >= off) ? s[t - off] : 0;
        __syncthreads();
        s[t] += add;
        __syncthreads();
    }
    int run = s[t] - loc;                       // exclusive prefix of chunk
#pragma unroll
    for (int k = 0; k < 4; ++k) {
        scan_out[b * NP1 + 4 * t + k] = run;    // contiguous store
        run += v[k];
    }
    if (t == 255) btotal[b] = s[255];
}

// ---- phase 3: bucket-grouped scatter (LDS cursors; in-block btotal scan) ----
__global__ __launch_bounds__(256) void k_scatter(const int* __restrict__ src,
                                                 const int* __restrict__ dst,
                                                 const int* __restrict__ scan_out,
                                                 const int* __restrict__ btotal,
                                                 unsigned* __restrict__ bucketed,
                                                 int E, int B, int chunk) {
    __shared__ int cur[MAXB];
    __shared__ int s[256];
    const int t = threadIdx.x;
    const int g = blockIdx.x;
    // exclusive scan of btotal (pairs), fused with cursor init
    int a0 = (2 * t     < B) ? btotal[2 * t]     : 0;
    int a1 = (2 * t + 1 < B) ? btotal[2 * t + 1] : 0;
    int pair = a0 + a1;
    s[t] = pair;
    __syncthreads();
    for (int off = 1; off < 256; off <<= 1) {
        int add = (t >= off) ? s[t - off] : 0;
        __syncthreads();
        s[t] += add;
        __syncthreads();
    }
    int ex = s[t] - pair;
    if (2 * t     < B) cur[2 * t]     = ex      + scan_out[(2 * t)     * NP1 + g];
    if (2 * t + 1 < B) cur[2 * t + 1] = ex + a0 + scan_out[(2 * t + 1) * NP1 + g];
    __syncthreads();
    const int e0 = g * chunk;
    const int e1 = min(E, e0 + chunk);
    const int cnt = e1 - e0;
    if (cnt <= 0) return;
    if ((E & 3) == 0) {                         // aligned int4 path
        const int nv = cnt >> 2;
        const int4* s4 = (const int4*)(src + e0);
        const int4* d4 = (const int4*)(dst + e0);
        for (int i = t; i < nv; i += 256) {
            int4 sv = s4[i];
            int4 dv = d4[i];
            int p0 = atomicAdd(&cur[dv.x >> BSH], 1);
            int p1 = atomicAdd(&cur[dv.y >> BSH], 1);
            int p2 = atomicAdd(&cur[dv.z >> BSH], 1);
            int p3 = atomicAdd(&cur[dv.w >> BSH], 1);
            bucketed[p0] = (unsigned)sv.x | ((unsigned)(dv.x & 255) << 17);
            bucketed[p1] = (unsigned)sv.y | ((unsigned)(dv.y & 255) << 17);
            bucketed[p2] = (unsigned)sv.z | ((unsigned)(dv.z & 255) << 17);
            bucketed[p3] = (unsigned)sv.w | ((unsigned)(dv.w & 255) << 17);
        }
        for (int e = e0 + (nv << 2) + t; e < e1; e += 256) {
            int d = dst[e];
            int p = atomicAdd(&cur[d >> BSH], 1);
            bucketed[p] = (unsigned)src[e] | ((unsigned)(d & 255) << 17);
        }
    } else {                                    // alignment fallback
        for (int e = e0 + t; e < e1; e += 256) {
            int d = dst[e];
            int p = atomicAdd(&cur[d >> BSH], 1);
            bucketed[p] = (unsigned)src[e] | ((unsigned)(d & 255) << 17);
        }
    }
}

// ---- phase 4: per-bucket CSR finalize (256 nodes/bucket) ----------------
__global__ __launch_bounds__(256) void k_csr(const unsigned* __restrict__ bucketed,
                                             const int* __restrict__ btotal,
                                             int* __restrict__ csr_src,
                                             int* __restrict__ rowptr,   // N+1
                                             float* __restrict__ dinv_g,
                                             int E, int B, int N) {
    const int b = blockIdx.x;
    const int t = threadIdx.x;
    __shared__ int sb[MAXB];
    __shared__ int s[256];
    __shared__ int sdeg[256], sscan[256], cur[256];
    // exclusive scan of btotal -> sb (bucket bases)
    int a0 = (2 * t     < B) ? btotal[2 * t]     : 0;
    int a1 = (2 * t + 1 < B) ? btotal[2 * t + 1] : 0;
    int pair = a0 + a1;
    s[t] = pair;
    sdeg[t] = 0;
    __syncthreads();
    for (int off = 1; off < 256; off <<= 1) {
        int add = (t >= off) ? s[t - off] : 0;
        __syncthreads();
        s[t] += add;
        __syncthreads();
    }
    int ex = s[t] - pair;
    if (2 * t     < B) sb[2 * t]     = ex;
    if (2 * t + 1 < B) sb[2 * t + 1] = ex + a0;
    __syncthreads();

    const int base = sb[b];
    const int cnt = btotal[b];
    const int node0 = b << BSH;

    for (int i = t; i < cnt; i += 256)
        atomicAdd(&sdeg[bucketed[base + i] >> 17], 1);
    __syncthreads();
    sscan[t] = sdeg[t];
    __syncthreads();
    for (int off = 1; off < 256; off <<= 1) {
        int add = (t >= off) ? sscan[t - off] : 0;
        __syncthreads();
        sscan[t] += add;
        __syncthreads();
    }
    {
        int rs = sscan[t] - sdeg[t];   // exclusive
        cur[t] = rs;
        int node = node0 + t;
        if (node < N) {
            rowptr[node] = base + rs;
            dinv_g[node] = rsqrtf((float)(sdeg[t] + 1));   // +1 self-loop
        }
    }
    if (b == B - 1 && t == 0) rowptr[N] = E;
    __syncthreads();
    for (int i = t; i < cnt; i += 256) {
        unsigned w = bucketed[base + i];
        int p = atomicAdd(&cur[w >> 17], 1);   // LDS atomic
        csr_src[base + p] = (int)(w & 0x1FFFFu);
    }
}

// ---- MFMA gemm: xs = bf16(dinv * (x @ W)), packed bf16x2 ----------------
// Wt staged into LDS once per block, XOR-swizzled (chunk c16 at c16^(row&7)).
// 2 row-tiles per wave; B-fragments via ds_read_b128 (uniform 8/bank = free).
// Grid (N+128)>>7 covers dummy row N: the grow2==N lane-group writes zeros.
__global__ __launch_bounds__(256) void k_gemm(const float* __restrict__ x,
                                              const unsigned short* __restrict__ Wt,
                                              const float* __restrict__ dinv,
                                              unsigned* __restrict__ xs_out, int N) {
    __shared__ uint4 wt_lds[128][16];           // 32 KB swizzled Wt
    __shared__ short out_lds[8][16][136];       // [wv*2+tile][row][col] wave-private
    const int t = threadIdx.x;
    const int wv = t >> 6;
    const int lane = t & 63;
    const int quad = lane >> 4;
    const int lid = lane & 15;
    const int row0 = blockIdx.x * 128 + wv * 32;   // this wave's 32 rows

    // stage Wt -> LDS, swizzled (8 x uint4 per thread, one-time)
    {
        const uint4* wg = (const uint4*)Wt;     // 2048 chunks of 16 B
#pragma unroll
        for (int i = 0; i < 8; ++i) {
            int g16 = t * 8 + i;
            int r = g16 >> 4, c16 = g16 & 15;
            wt_lds[r][c16 ^ (r & 7)] = wg[g16];
        }
    }

    // load + convert x tiles BEFORE the barrier (HBM latency hides under staging)
    short8 af0[4], af1[4];
    {
        int r0 = row0 + lid;       int r0c = r0 < N ? r0 : N - 1;
        int r1 = row0 + 16 + lid;  int r1c = r1 < N ? r1 : N - 1;
#pragma unroll
        for (int q = 0; q < 4; ++q) {
            const float4* xr0 = (const float4*)(x + (size_t)r0c * 128 + q * 32 + quad * 8);
            const float4* xr1 = (const float4*)(x + (size_t)r1c * 128 + q * 32 + quad * 8);
            float4 f0 = xr0[0], f1 = xr0[1];
            float4 g0 = xr1[0], g1 = xr1[1];
            af0[q][0] = (short)f2b(f0.x); af0[q][1] = (short)f2b(f0.y);
            af0[q][2] = (short)f2b(f0.z); af0[q][3] = (short)f2b(f0.w);
            af0[q][4] = (short)f2b(f1.x); af0[q][5] = (short)f2b(f1.y);
            af0[q][6] = (short)f2b(f1.z); af0[q][7] = (short)f2b(f1.w);
            af1[q][0] = (short)f2b(g0.x); af1[q][1] = (short)f2b(g0.y);
            af1[q][2] = (short)f2b(g0.z); af1[q][3] = (short)f2b(g0.w);
            af1[q][4] = (short)f2b(g1.x); af1[q][5] = (short)f2b(g1.y);
            af1[q][6] = (short)f2b(g1.z); af1[q][7] = (short)f2b(g1.w);
        }
    }

    float4 dv0, dv1;
    {
        int dr0 = row0 + quad * 4;
        int dr1 = row0 + 16 + quad * 4;
        if (dr0 + 3 < N) dv0 = *(const float4*)(dinv + dr0);
        else {
            dv0.x = dinv[min(dr0 + 0, N - 1)];
            dv0.y = dinv[min(dr0 + 1, N - 1)];
            dv0.z = dinv[min(dr0 + 2, N - 1)];
            dv0.w = dinv[min(dr0 + 3, N - 1)];
        }
        if (dr1 + 3 < N) dv1 = *(const float4*)(dinv + dr1);
        else {
            dv1.x = dinv[min(dr1 + 0, N - 1)];
            dv1.y = dinv[min(dr1 + 1, N - 1)];
            dv1.z = dinv[min(dr1 + 2, N - 1)];
            dv1.w = dinv[min(dr1 + 3, N - 1)];
        }
    }

    __syncthreads();                            // wt_lds ready

#pragma unroll
    for (int c = 0; c < 8; ++c) {
        f32x4 a0 = {0.f, 0.f, 0.f, 0.f};
        f32x4 a1 = {0.f, 0.f, 0.f, 0.f};
        const int r = c * 16 + lid;             // Wt row this lane needs
        const int rx = r & 7;
#pragma unroll
        for (int q = 0; q < 4; ++q) {
            short8 bq = *(const short8*)&wt_lds[r][(q * 4 + quad) ^ rx];
            a0 = __builtin_amdgcn_mfma_f32_16x16x32_bf16(af0[q], bq, a0, 0, 0, 0);
            a1 = __builtin_amdgcn_mfma_f32_16x16x32_bf16(af1[q], bq, a1, 0, 0, 0);
        }
        const int sb = wv * 2;
        out_lds[sb + 0][quad * 4 + 0][c * 16 + lid] = (short)f2b(a0[0] * dv0.x);
        out_lds[sb + 0][quad * 4 + 1][c * 16 + lid] = (short)f2b(a0[1] * dv0.y);
        out_lds[sb + 0][quad * 4 + 2][c * 16 + lid] = (short)f2b(a0[2] * dv0.z);
        out_lds[sb + 0][quad * 4 + 3][c * 16 + lid] = (short)f2b(a0[3] * dv0.w);
        out_lds[sb + 1][quad * 4 + 0][c * 16 + lid] = (short)f2b(a1[0] * dv1.x);
        out_lds[sb + 1][quad * 4 + 1][c * 16 + lid] = (short)f2b(a1[1] * dv1.y);
        out_lds[sb + 1][quad * 4 + 2][c * 16 + lid] = (short)f2b(a1[2] * dv1.z);
        out_lds[sb + 1][quad * 4 + 3][c * 16 + lid] = (short)f2b(a1[3] * dv1.w);
    }
    // no second barrier: out_lds[wv*2+tl] is written and read only by wave wv

    const int rl = lane >> 2;
    const int cseg = lane & 3;
#pragma unroll
    for (int tl = 0; tl < 2; ++tl) {
        int grow2 = row0 + tl * 16 + rl;
        if (grow2 <= N) {
            uint4* dstp = (uint4*)(xs_out + (size_t)grow2 * 64);
            if (grow2 < N) {
                const uint4* srcp = (const uint4*)((const char*)&out_lds[wv * 2 + tl][rl][0] + cseg * 64);
#pragma unroll
                for (int tt = 0; tt < 4; ++tt) dstp[cseg * 4 + tt] = srcp[tt];
            } else {                              // dummy zero row at index N
                uint4 z = make_uint4(0u, 0u, 0u, 0u);
#pragma unroll
                for (int tt = 0; tt < 4; ++tt) dstp[cseg * 4 + tt] = z;
            }
        }
    }
}

// ---- aggregate: 4 nodes/wave, 16 lanes/node, 8 feats/lane ----------------
// 8 gathers in flight per round; next round's csr indices prefetched during
// gathers; tail slots gather the zeroed row N (hot line). NT out stores.
__global__ __launch_bounds__(256) void k_aggregate(const uint4* __restrict__ xs4,
                                                   const int* __restrict__ csr_src,
                                                   const int* __restrict__ rowptr,
                                                   const float* __restrict__ dinv,
                                                   const float* __restrict__ bias,
                                                   float* __restrict__ out, int N) {
    const int t = threadIdx.x;
    const int lane = t & 63;
    const int sub = lane & 15;           // feature quarter: 8 floats (one uint4)
    const int gbase = lane & 48;         // 16-lane group base within wave
    const int n = blockIdx.x * 16 + (t >> 4);
    if (n >= N) return;

    const int rs = rowptr[n];
    const int re = rowptr[n + 1];
    const float dv = dinv[n];
    const char* xb = (const char*)xs4;
    const unsigned subo = (unsigned)sub << 4;

    float4 a0 = make_float4(0.f, 0.f, 0.f, 0.f);
    float4 a1 = make_float4(0.f, 0.f, 0.f, 0.f);

    int idx = N;                                  // dummy zero row for tail slots
    if (rs + sub < re) idx = csr_src[rs + sub];

    for (int i0 = rs; i0 < re; i0 += 16) {
        const int idx_cur = idx;
        const int i1 = i0 + 16;
        idx = N;                                  // prefetch next round's index
        if (i1 + sub < re) idx = csr_src[i1 + sub];
        int m = re - i0; if (m > 16) m = 16;

        {   // slots 0..7: 8 gathers in flight
            int r0 = __shfl(idx_cur, gbase + 0);
            int r1 = __shfl(idx_cur, gbase + 1);
            int r2 = __shfl(idx_cur, gbase + 2);
            int r3 = __shfl(idx_cur, gbase + 3);
            int r4 = __shfl(idx_cur, gbase + 4);
            int r5 = __shfl(idx_cur, gbase + 5);
            int r6 = __shfl(idx_cur, gbase + 6);
            int r7 = __shfl(idx_cur, gbase + 7);
            uint4 u0 = *(const uint4*)(xb + ((((unsigned)r0) << 8) | subo));
            uint4 u1 = *(const uint4*)(xb + ((((unsigned)r1) << 8) | subo));
            uint4 u2 = *(const uint4*)(xb + ((((unsigned)r2) << 8) | subo));
            uint4 u3 = *(const uint4*)(xb + ((((unsigned)r3) << 8) | subo));
            uint4 u4 = *(const uint4*)(xb + ((((unsigned)r4) << 8) | subo));
            uint4 u5 = *(const uint4*)(xb + ((((unsigned)r5) << 8) | subo));
            uint4 u6 = *(const uint4*)(xb + ((((unsigned)r6) << 8) | subo));
            uint4 u7 = *(const uint4*)(xb + ((((unsigned)r7) << 8) | subo));
            acc4(a0, u0.x, u0.y); acc4(a1, u0.z, u0.w);
            acc4(a0, u1.x, u1.y); acc4(a1, u1.z, u1.w);
            acc4(a0, u2.x, u2.y); acc4(a1, u2.z, u2.w);
            acc4(a0, u3.x, u3.y); acc4(a1, u3.z, u3.w);
            acc4(a0, u4.x, u4.y); acc4(a1, u4.z, u4.w);
            acc4(a0, u5.x, u5.y); acc4(a1, u5.z, u5.w);
            acc4(a0, u6.x, u6.y); acc4(a1, u6.z, u6.w);
            acc4(a0, u7.x, u7.y); acc4(a1, u7.z, u7.w);
        }
        if (m > 8) {   // slots 8..15
            int r0 = __shfl(idx_cur, gbase + 8);
            int r1 = __shfl(idx_cur, gbase + 9);
            int r2 = __shfl(idx_cur, gbase + 10);
            int r3 = __shfl(idx_cur, gbase + 11);
            int r4 = __shfl(idx_cur, gbase + 12);
            int r5 = __shfl(idx_cur, gbase + 13);
            int r6 = __shfl(idx_cur, gbase + 14);
            int r7 = __shfl(idx_cur, gbase + 15);
            uint4 u0 = *(const uint4*)(xb + ((((unsigned)r0) << 8) | subo));
            uint4 u1 = *(const uint4*)(xb + ((((unsigned)r1) << 8) | subo));
            uint4 u2 = *(const uint4*)(xb + ((((unsigned)r2) << 8) | subo));
            uint4 u3 = *(const uint4*)(xb + ((((unsigned)r3) << 8) | subo));
            uint4 u4 = *(const uint4*)(xb + ((((unsigned)r4) << 8) | subo));
            uint4 u5 = *(const uint4*)(xb + ((((unsigned)r5) << 8) | subo));
            uint4 u6 = *(const uint4*)(xb + ((((unsigned)r6) << 8) | subo));
            uint4 u7 = *(const uint4*)(xb + ((((unsigned)r7) << 8) | subo));
            acc4(a0, u0.x, u0.y); acc4(a1, u0.z, u0.w);
            acc4(a0, u1.x, u1.y); acc4(a1, u1.z, u1.w);
            acc4(a0, u2.x, u2.y); acc4(a1, u2.z, u2.w);
            acc4(a0, u3.x, u3.y); acc4(a1, u3.z, u3.w);
            acc4(a0, u4.x, u4.y); acc4(a1, u4.z, u4.w);
            acc4(a0, u5.x, u5.y); acc4(a1, u5.z, u5.w);
            acc4(a0, u6.x, u6.y); acc4(a1, u6.z, u6.w);
            acc4(a0, u7.x, u7.y); acc4(a1, u7.z, u7.w);
        }
    }

    // self-loop (xs row n already dinv[n]-scaled)
    uint4 su = *(const uint4*)(xb + ((((unsigned)n) << 8) | subo));
    acc4(a0, su.x, su.y);
    acc4(a1, su.z, su.w);

    const float4* bp = (const float4*)bias;
    float4 b0 = bp[sub * 2];
    float4 b1 = bp[sub * 2 + 1];
    f32x4 o0, o1;
    o0[0] = fmaxf(dv * a0.x + b0.x, 0.f);
    o0[1] = fmaxf(dv * a0.y + b0.y, 0.f);
    o0[2] = fmaxf(dv * a0.z + b0.z, 0.f);
    o0[3] = fmaxf(dv * a0.w + b0.w, 0.f);
    o1[0] = fmaxf(dv * a1.x + b1.x, 0.f);
    o1[1] = fmaxf(dv * a1.y + b1.y, 0.f);
    o1[2] = fmaxf(dv * a1.z + b1.z, 0.f);
    o1[3] = fmaxf(dv * a1.w + b1.w, 0.f);

    f32x4* op = (f32x4*)(out + (size_t)n * 128 + sub * 8);
    __builtin_nontemporal_store(o0, op);          // out is write-once: don't
    __builtin_nontemporal_store(o1, op + 1);      // evict xs gather lines
}

extern "C" void kernel_launch(void* const* d_in, const int* in_sizes, int n_in,
                              void* d_out, int out_size, void* d_ws, size_t ws_size,
                              hipStream_t stream) {
    const float* x   = (const float*)d_in[0];
    const int*   ei  = (const int*)d_in[1];     // [2, E] flat: src then dst
    const float* W   = (const float*)d_in[2];
    const float* b   = (const float*)d_in[3];
    float*       out = (float*)d_out;

    const int N = in_sizes[0] / 128;
    const int E = in_sizes[1] / 2;
    const int* src = ei;
    const int* dst = ei + E;

    const int B = (N + 255) >> BSH;          // 392 buckets (<= MAXB)
    const int M = B * NP1;                   // hist entries
    // edges per phase-1 block, rounded to 4 for int4 alignment
    const int chunk = (((E + NP1 - 1) / NP1) + 3) & ~3;

    // workspace carve (256B aligned)
    auto align = [](size_t v) { return (v + 255) & ~(size_t)255; };
    char* p = (char*)d_ws;
    int*            hist     = (int*)p;            p += align((size_t)M * 4);
    int*            scan_out = (int*)p;            p += align((size_t)M * 4);
    int*            btotal   = (int*)p;            p += align((size_t)B * 4);
    int*            rowptr   = (int*)p;            p += align(((size_t)N + 1) * 4);
    float*          dinv     = (float*)p;          p += align((size_t)N * 4);
    unsigned*       bucketed = (unsigned*)p;       p += align((size_t)E * 4);
    int*            csr_src  = (int*)p;            p += align((size_t)E * 4);
    unsigned*       xs       = (unsigned*)p;       p += align(((size_t)N + 1) * 64 * 4);
    unsigned short* Wt       = (unsigned short*)p; p += align(128 * 128 * 2);
    (void)ws_size;

    k_hist    <<<NP1, 256, 0, stream>>>(dst, hist, W, Wt, E, B, chunk);
    k_scanrow <<<B, 256, 0, stream>>>(hist, scan_out, btotal, B);
    k_scatter <<<NP1, 256, 0, stream>>>(src, dst, scan_out, btotal, bucketed, E, B, chunk);
    k_csr     <<<B, 256, 0, stream>>>(bucketed, btotal, csr_src, rowptr,
                                      dinv, E, B, N);
    k_gemm    <<<(N + 128) >> 7, 256, 0, stream>>>(x, Wt, dinv, xs, N);  // covers row N
    k_aggregate<<<(N + 15) / 16, 256, 0, stream>>>((const uint4*)xs, csr_src, rowptr,
                                                   dinv, b, out, N);
}